// Round 7
// baseline (1350.966 us; speedup 1.0000x reference)
//
#include <hip/hip_runtime.h>
#include <math.h>

// Problem constants (B=4, L=2048, D=1024, H=4, DK=DV=256, CHUNK=32)
#define NTOK   8192      // B*L
#define LSEQ   2048
#define NCHUNK 64        // L/32

typedef short bhalf8 __attribute__((ext_vector_type(8)));
typedef float floatx4 __attribute__((ext_vector_type(4)));

__device__ inline ushort f2bf(float f) {
  uint u = __float_as_uint(f);
  u += 0x7FFFu + ((u >> 16) & 1u);
  return (ushort)(u >> 16);
}
__device__ inline float bf2f(ushort h) {
  return __uint_as_float(((uint)h) << 16);
}

#define GLD_LDS16(g, s) __builtin_amdgcn_global_load_lds(                      \
    (const __attribute__((address_space(1))) void*)(g),                        \
    (__attribute__((address_space(3))) void*)(s), 16, 0, 0)

// ---------------------------------------------------------------------------
// f32 -> bf16 copy (n8 = elements/8)
// ---------------------------------------------------------------------------
__global__ __launch_bounds__(256)
void cvt_bf16(const float* __restrict__ x, ushort* __restrict__ y, int n8) {
  int i = blockIdx.x * 256 + threadIdx.x;
  if (i >= n8) return;
  const float4* xp = (const float4*)x;
  float4 a = xp[2 * i], b = xp[2 * i + 1];
  uint4 o;
  o.x = (uint)f2bf(a.x) | ((uint)f2bf(a.y) << 16);
  o.y = (uint)f2bf(a.z) | ((uint)f2bf(a.w) << 16);
  o.z = (uint)f2bf(b.x) | ((uint)f2bf(b.y) << 16);
  o.w = (uint)f2bf(b.z) | ((uint)f2bf(b.w) << 16);
  ((uint4*)y)[i] = o;
}

// ---------------------------------------------------------------------------
// f32 [R][C] -> bf16 [C][R] transpose (weights). Grid (C/32, R/32), 256 thr.
// ---------------------------------------------------------------------------
__global__ __launch_bounds__(256)
void cvt_t(const float* __restrict__ x, ushort* __restrict__ y, int R, int C) {
  __shared__ float tile[32][33];
  int r0 = blockIdx.y * 32, c0 = blockIdx.x * 32;
  int tr = threadIdx.x >> 5;       // 0..7
  int tc = threadIdx.x & 31;
  #pragma unroll
  for (int rr = tr; rr < 32; rr += 8)
    tile[rr][tc] = x[(size_t)(r0 + rr) * C + c0 + tc];
  __syncthreads();
  #pragma unroll
  for (int rr = tr; rr < 32; rr += 8)
    y[(size_t)(c0 + rr) * R + r0 + tc] = f2bf(tile[tc][rr]);
}

// ---------------------------------------------------------------------------
// bf16 MFMA GEMM: C[M,N] = (ACC? C:0) + A[M,K] @ BT[N,K]^T
// 128x128 tile, BK=32, 256 thr (4 waves 2x2), 4x4 frags of 16x16x32.
// LDS tiles stored in MFMA FRAGMENT ORDER (subtile s = rows s*16..s*16+15;
// within subtile, lane slot l holds row s*16+(l&15), cols (l>>4)*8..+7) so
// ds_read_b128 is lane-linear -> zero bank conflicts.
// ---------------------------------------------------------------------------
template<int ACC>
__global__ __launch_bounds__(256)
void gemm_bf(const ushort* __restrict__ A, const ushort* __restrict__ BT,
             float* __restrict__ C, int K, int lda, int ldbt, int ldc) {
  __shared__ ushort Asm[128 * 32];
  __shared__ ushort Bsm[128 * 32];
  const int t = threadIdx.x;
  const int w = t >> 6, l = t & 63;
  const int m0 = blockIdx.y * 128, n0 = blockIdx.x * 128;
  const int wr = w >> 1, wc = w & 1;
  const int frow = l & 15;             // fragment row within subtile
  const int fcol = (l >> 4) * 8;       // fragment k-col

  floatx4 acc[4][4];
  #pragma unroll
  for (int i = 0; i < 4; i++)
    #pragma unroll
    for (int j = 0; j < 4; j++)
      #pragma unroll
      for (int r = 0; r < 4; r++) acc[i][j][r] = 0.f;

  for (int k0 = 0; k0 < K; k0 += 32) {
    __syncthreads();
    #pragma unroll
    for (int j = 0; j < 2; j++) {
      int sub = w * 2 + j;             // subtile 0..7
      int row = sub * 16 + frow;
      GLD_LDS16(A + (size_t)(m0 + row) * lda + k0 + fcol, Asm + sub * 512);
      GLD_LDS16(BT + (size_t)(n0 + row) * ldbt + k0 + fcol, Bsm + sub * 512);
    }
    __syncthreads();
    bhalf8 af[4], bf_[4];
    #pragma unroll
    for (int i = 0; i < 4; i++)
      af[i] = *(const bhalf8*)&Asm[(wr * 4 + i) * 512 + l * 8];
    #pragma unroll
    for (int j = 0; j < 4; j++)
      bf_[j] = *(const bhalf8*)&Bsm[(wc * 4 + j) * 512 + l * 8];
    #pragma unroll
    for (int i = 0; i < 4; i++)
      #pragma unroll
      for (int j = 0; j < 4; j++)
        acc[i][j] = __builtin_amdgcn_mfma_f32_16x16x32_bf16(af[i], bf_[j],
                                                            acc[i][j], 0, 0, 0);
  }
  const int crow = (l >> 4) * 4;
  const int ccol = l & 15;
  #pragma unroll
  for (int i = 0; i < 4; i++)
    #pragma unroll
    for (int j = 0; j < 4; j++) {
      float* cp = &C[(size_t)(m0 + wr * 64 + i * 16 + crow) * ldc +
                     n0 + wc * 64 + j * 16 + ccol];
      #pragma unroll
      for (int r = 0; r < 4; r++) {
        if (ACC) cp[(size_t)r * ldc] += acc[i][j][r];
        else     cp[(size_t)r * ldc]  = acc[i][j][r];
      }
    }
}

// ---------------------------------------------------------------------------
// Router GEMM: C[8192,1024] = gelu(sum_p A_p[8192,1024] @ W1T[1024,6144]^T
//                                   + b1half)   (bias+gelu fused epilogue)
// ---------------------------------------------------------------------------
struct APtrs { const ushort* p[6]; };

__global__ __launch_bounds__(256)
void gemm_router(APtrs ap, const ushort* __restrict__ BT,
                 const float* __restrict__ bias, float* __restrict__ C) {
  __shared__ ushort Asm[128 * 32];
  __shared__ ushort Bsm[128 * 32];
  const int t = threadIdx.x;
  const int w = t >> 6, l = t & 63;
  const int m0 = blockIdx.y * 128, n0 = blockIdx.x * 128;
  const int wr = w >> 1, wc = w & 1;
  const int frow = l & 15;
  const int fcol = (l >> 4) * 8;

  floatx4 acc[4][4];
  #pragma unroll
  for (int i = 0; i < 4; i++)
    #pragma unroll
    for (int j = 0; j < 4; j++)
      #pragma unroll
      for (int r = 0; r < 4; r++) acc[i][j][r] = 0.f;

  for (int k0 = 0; k0 < 6144; k0 += 32) {
    const ushort* Abase = ap.p[k0 >> 10];
    const int kk = k0 & 1023;
    __syncthreads();
    #pragma unroll
    for (int j = 0; j < 2; j++) {
      int sub = w * 2 + j;
      int row = sub * 16 + frow;
      GLD_LDS16(Abase + (size_t)(m0 + row) * 1024 + kk + fcol, Asm + sub * 512);
      GLD_LDS16(BT + (size_t)(n0 + row) * 6144 + k0 + fcol, Bsm + sub * 512);
    }
    __syncthreads();
    bhalf8 af[4], bf_[4];
    #pragma unroll
    for (int i = 0; i < 4; i++)
      af[i] = *(const bhalf8*)&Asm[(wr * 4 + i) * 512 + l * 8];
    #pragma unroll
    for (int j = 0; j < 4; j++)
      bf_[j] = *(const bhalf8*)&Bsm[(wc * 4 + j) * 512 + l * 8];
    #pragma unroll
    for (int i = 0; i < 4; i++)
      #pragma unroll
      for (int j = 0; j < 4; j++)
        acc[i][j] = __builtin_amdgcn_mfma_f32_16x16x32_bf16(af[i], bf_[j],
                                                            acc[i][j], 0, 0, 0);
  }
  const int crow = (l >> 4) * 4;
  const int ccol = l & 15;
  #pragma unroll
  for (int i = 0; i < 4; i++)
    #pragma unroll
    for (int j = 0; j < 4; j++) {
      const int col = n0 + wc * 64 + j * 16 + ccol;
      const float bb = bias[col];
      float* cp = &C[(size_t)(m0 + wr * 64 + i * 16 + crow) * 1024 + col];
      #pragma unroll
      for (int r = 0; r < 4; r++) {
        float x = acc[i][j][r] + bb;
        cp[(size_t)r * 1024] = 0.5f * x * (1.f + erff(x * 0.70710678118654752f));
      }
    }
}

// ---------------------------------------------------------------------------
// Causal depthwise conv (K=4) + SiLU.  x,y: (B*L, 1024) f32.
// ---------------------------------------------------------------------------
__global__ __launch_bounds__(256)
void conv4_silu(const float* __restrict__ x, const float* __restrict__ w,
                float* __restrict__ y) {
  int idx = blockIdx.x * 256 + threadIdx.x;
  int c = idx & 1023;
  int bl = idx >> 10;
  int l = bl & (LSEQ - 1);
  float w0 = w[c * 4 + 0], w1 = w[c * 4 + 1], w2 = w[c * 4 + 2], w3 = w[c * 4 + 3];
  float acc = x[idx] * w3;
  if (l >= 1) acc += x[idx - 1024] * w2;
  if (l >= 2) acc += x[idx - 2048] * w1;
  if (l >= 3) acc += x[idx - 3072] * w0;
  y[idx] = acc / (1.f + expf(-acc));
}

// ---------------------------------------------------------------------------
// Pack FIR weights transposed: fwTp[row][c], rows 0..2=f3(j), 3..9=f7(j),
// 10..24=f15(j), 25..55=f31(j).
// ---------------------------------------------------------------------------
__global__ __launch_bounds__(256)
void pack_fir(const float* __restrict__ f3w, const float* __restrict__ f7w,
              const float* __restrict__ f15w, const float* __restrict__ f31w,
              float* __restrict__ fwTp) {
  int i = blockIdx.x * 256 + threadIdx.x;   // 56*1024
  if (i >= 57344) return;
  int row = i >> 10, c = i & 1023;
  float val;
  if (row < 3)       val = f3w[c * 3 + row];
  else if (row < 10) val = f7w[c * 7 + (row - 3)];
  else if (row < 25) val = f15w[c * 15 + (row - 10)];
  else               val = f31w[c * 31 + (row - 25)];
  fwTp[i] = val;
}

// ---------------------------------------------------------------------------
// All 4 depthwise causal FIRs in one pass. bf16 outputs.
// ---------------------------------------------------------------------------
__global__ __launch_bounds__(256)
void fir_all(const float* __restrict__ v, const float* __restrict__ fwTp,
             ushort* __restrict__ y3, ushort* __restrict__ y7,
             ushort* __restrict__ y15, ushort* __restrict__ y31) {
  int idx = blockIdx.x * 256 + threadIdx.x;   // over 8192*1024
  int c = idx & 1023;
  int l = (idx >> 10) & (LSEQ - 1);
  float a3 = 0.f, a7 = 0.f, a15 = 0.f, a31 = 0.f;
  #pragma unroll
  for (int back = 30; back >= 0; back--) {
    float x = (l >= back) ? v[idx - back * 1024] : 0.f;
    a31 += x * fwTp[(25 + 30 - back) * 1024 + c];
    if (back <= 14) a15 += x * fwTp[(10 + 14 - back) * 1024 + c];
    if (back <= 6)  a7  += x * fwTp[(3 + 6 - back) * 1024 + c];
    if (back <= 2)  a3  += x * fwTp[(2 - back) * 1024 + c];
  }
  y3[idx]  = f2bf(a3);
  y7[idx]  = f2bf(a7);
  y15[idx] = f2bf(a15);
  y31[idx] = f2bf(a31);
}

// ---------------------------------------------------------------------------
// beta = sigmoid(hs@Wb), p_value = sigmoid(hs@idW + idb); one wave per (tok,h)
// ---------------------------------------------------------------------------
__global__ __launch_bounds__(256)
void beta_pv(const float* __restrict__ hs, const float* __restrict__ Wb,
             const float* __restrict__ idW, const float* __restrict__ idb,
             float* __restrict__ beta, float* __restrict__ pv) {
  int tok = blockIdx.x;
  int h = threadIdx.x >> 6;
  int lane = threadIdx.x & 63;
  const float* hrow = hs + (size_t)tok * 1024;
  float s1 = 0.f, s2 = 0.f;
  #pragma unroll
  for (int j = 0; j < 16; j++) {
    int d = lane + j * 64;
    float hv = hrow[d];
    s1 += hv * Wb[d * 4 + h];
    s2 += hv * idW[d * 4 + h];
  }
  #pragma unroll
  for (int off = 32; off; off >>= 1) {
    s1 += __shfl_down(s1, off);
    s2 += __shfl_down(s2, off);
  }
  if (lane == 0) {
    beta[tok * 4 + h] = 1.f / (1.f + expf(-s1));
    pv[tok * 4 + h] = 1.f / (1.f + expf(-(s2 + idb[h])));
  }
}

// ---------------------------------------------------------------------------
// In-place l2norm of q and k per (tok, head) over 256 dims. Wave per (tok,h).
// ---------------------------------------------------------------------------
__global__ __launch_bounds__(256)
void l2norm_qk(float* __restrict__ q, float* __restrict__ k) {
  int tok = blockIdx.x;
  int h = threadIdx.x >> 6;
  int lane = threadIdx.x & 63;
  size_t base = (size_t)tok * 1024 + h * 256 + lane * 4;
  {
    float4* p = (float4*)(q + base);
    float4 v = *p;
    float ss = v.x * v.x + v.y * v.y + v.z * v.z + v.w * v.w;
    #pragma unroll
    for (int off = 32; off; off >>= 1) ss += __shfl_xor(ss, off);
    float sc = rsqrtf(ss + 1e-6f);
    v.x *= sc; v.y *= sc; v.z *= sc; v.w *= sc;
    *p = v;
  }
  {
    float4* p = (float4*)(k + base);
    float4 v = *p;
    float ss = v.x * v.x + v.y * v.y + v.z * v.z + v.w * v.w;
    #pragma unroll
    for (int off = 32; off; off >>= 1) ss += __shfl_xor(ss, off);
    float sc = rsqrtf(ss + 1e-6f);
    v.x *= sc; v.y *= sc; v.z *= sc; v.w *= sc;
    *p = v;
  }
}

// ---------------------------------------------------------------------------
// Per-(b,h,chunk): att = tril(q k^T) [bf16 frag-order], forward substitution
// u = T^{-1}(v*beta) [f32], w = T^{-1}(k*beta) [bf16 frag-order],
// q and k^T [bf16 frag-order] for the MFMA scan.
// ---------------------------------------------------------------------------
__global__ __launch_bounds__(256)
void chunk_prep(const float* __restrict__ q, const float* __restrict__ k,
                const float* __restrict__ v, const float* __restrict__ beta,
                ushort* __restrict__ attf, float* __restrict__ ub,
                ushort* __restrict__ wfb, ushort* __restrict__ qfb,
                ushort* __restrict__ ktb) {
  __shared__ float kbuf[32 * 260];
  __shared__ float qbuf[32 * 260];
  __shared__ float Am[32 * 32];
  __shared__ float bet[32];
  const int t = threadIdx.x;
  const int blk = blockIdx.x;          // ((b*4+h)*64 + n)
  const int n = blk & 63, bh = blk >> 6;
  const int h = bh & 3, b = bh >> 2;
  const size_t rowbase = (size_t)b * LSEQ + n * 32;
  const int cbase = h * 256;
  const int srow = t >> 6, scol = (t & 63) * 4;
  const size_t fb = (size_t)blk * 8192;   // frag-buffer base (ushort)

  #pragma unroll
  for (int rep = 0; rep < 8; rep++) {
    int r = rep * 4 + srow;
    *(float4*)&kbuf[r * 260 + scol] =
        *(const float4*)&k[(rowbase + r) * 1024 + cbase + scol];
    *(float4*)&qbuf[r * 260 + scol] =
        *(const float4*)&q[(rowbase + r) * 1024 + cbase + scol];
  }
  if (t < 32) bet[t] = beta[(rowbase + t) * 4 + h];
  __syncthreads();

  // att (bf16 frag order) + A
  #pragma unroll
  for (int e = 0; e < 4; e++) {
    int idx = t + e * 256;
    int i = idx >> 5, jc = idx & 31;
    float da = 0.f, dq = 0.f;
    for (int d0 = 0; d0 < 256; d0 += 4) {
      float4 kj = *(float4*)&kbuf[jc * 260 + d0];
      float4 ki = *(float4*)&kbuf[i * 260 + d0];
      float4 qi = *(float4*)&qbuf[i * 260 + d0];
      da += ki.x * kj.x + ki.y * kj.y + ki.z * kj.z + ki.w * kj.w;
      dq += qi.x * kj.x + qi.y * kj.y + qi.z * kj.z + qi.w * kj.w;
    }
    Am[i * 32 + jc] = (jc < i) ? bet[i] * da : 0.f;
    float av = (jc <= i) ? dq : 0.f;
    attf[(size_t)blk * 1024 + (i >> 4) * 512 +
         ((i & 15) + ((jc >> 3) & 3) * 16) * 8 + (jc & 7)] = f2bf(av);
  }
  __syncthreads();

  // k^T frag writes (A-operand, M=dk 256, K=c 32), pre-substitution.
  #pragma unroll
  for (int cg = 0; cg < 4; cg++) {
    bhalf8 pk;
    #pragma unroll
    for (int j = 0; j < 8; j++)
      pk[j] = (short)f2bf(kbuf[(cg * 8 + j) * 260 + t]);
    *(bhalf8*)&ktb[fb + (t >> 4) * 512 + ((t & 15) + cg * 16) * 8] = pk;
  }

  // k -> w in place (thread owns column t; column-private)
  #pragma unroll 1
  for (int i = 0; i < 32; i++) {
    float val = bet[i] * kbuf[i * 260 + t];
    for (int j = 0; j < i; j++) val -= Am[i * 32 + j] * kbuf[j * 260 + t];
    kbuf[i * 260 + t] = val;
  }
  __syncthreads();   // w stable for cross-column repack

  // w and q frag repack: pack p -> (c = p&31, dk8 = p>>5)
  #pragma unroll
  for (int rep = 0; rep < 4; rep++) {
    int p = rep * 256 + t;
    int c = p & 31, dk8 = p >> 5;
    size_t pos = fb + ((size_t)(dk8 >> 2) * 2 + (c >> 4)) * 512 +
                 ((c & 15) + (dk8 & 3) * 16) * 8;
    bhalf8 pw, pq;
    #pragma unroll
    for (int j = 0; j < 8; j++) {
      pw[j] = (short)f2bf(kbuf[c * 260 + dk8 * 8 + j]);
      pq[j] = (short)f2bf(qbuf[c * 260 + dk8 * 8 + j]);
    }
    *(bhalf8*)&wfb[pos] = pw;
    *(bhalf8*)&qfb[pos] = pq;
  }
  __syncthreads();

  // v into qbuf, then v -> u (f32)
  #pragma unroll
  for (int rep = 0; rep < 8; rep++) {
    int r = rep * 4 + srow;
    *(float4*)&qbuf[r * 260 + scol] =
        *(const float4*)&v[(rowbase + r) * 1024 + cbase + scol];
  }
  __syncthreads();
  #pragma unroll 1
  for (int i = 0; i < 32; i++) {
    float val = bet[i] * qbuf[i * 260 + t];
    for (int j = 0; j < i; j++) val -= Am[i * 32 + j] * qbuf[j * 260 + t];
    qbuf[i * 260 + t] = val;
  }
  for (int j = 0; j < 32; j++)
    ub[(rowbase + j) * 1024 + cbase + t] = qbuf[j * 260 + t];
}

// ---------------------------------------------------------------------------
// MFMA delta scan. Block per (b,h,dv-slice of 16): 256 blocks, 4 waves.
// S (256x16) lives as f32 MFMA accumulators (4 frags/wave, K-split by wave).
// ---------------------------------------------------------------------------
__global__ __launch_bounds__(256)
void delta_scan(const ushort* __restrict__ wfb, const ushort* __restrict__ qfb,
                const ushort* __restrict__ ktb, const ushort* __restrict__ attf,
                const float* __restrict__ ub, ushort* __restrict__ outb) {
  __shared__ ushort wS[8192];
  __shared__ ushort qS[8192];
  __shared__ ushort kTS[8192];
  __shared__ ushort attS[1024];
  __shared__ ushort SbT[16 * 264];
  __shared__ ushort uaT[16 * 40];
  __shared__ float pbufW[4 * 544];
  __shared__ float pbufQ[4 * 544];
  __shared__ float oacc[544];
  const int t = threadIdx.x;
  const int w = t >> 6, l = t & 63;
  const int col16 = l & 15, g = l >> 4;
  const int blk = blockIdx.x;
  const int dsl = blk & 15, bh = blk >> 4;
  const int h = bh & 3, b = bh >> 2;
  const int dbase = h * 256 + dsl * 16;

  floatx4 S_acc[4];
  #pragma unroll
  for (int m = 0; m < 4; m++)
    #pragma unroll
    for (int r = 0; r < 4; r++) S_acc[m][r] = 0.f;

  for (int n = 0; n < NCHUNK; n++) {
    const size_t cb = ((size_t)(bh * 64 + n)) * 8192;
    const size_t ab = ((size_t)(bh * 64 + n)) * 1024;
    const size_t rowbase = (size_t)b * LSEQ + n * 32;

    // SbT <- bf16(S_acc): lane holds rows w*64+m*16+g*4+{0..3}, col col16
    #pragma unroll
    for (int m = 0; m < 4; m++) {
      uint lo = (uint)f2bf(S_acc[m][0]) | ((uint)f2bf(S_acc[m][1]) << 16);
      uint hi = (uint)f2bf(S_acc[m][2]) | ((uint)f2bf(S_acc[m][3]) << 16);
      uint2 pk; pk.x = lo; pk.y = hi;
      *(uint2*)&SbT[col16 * 264 + w * 64 + m * 16 + g * 4] = pk;
    }
    // stage w/q/kT (16 KB each) + att (2 KB) via global_load_lds
    #pragma unroll
    for (int i = 0; i < 4; i++) {
      GLD_LDS16(wfb + cb + (w * 4 + i) * 512 + l * 8, &wS[(w * 4 + i) * 512]);
      GLD_LDS16(qfb + cb + (w * 4 + i) * 512 + l * 8, &qS[(w * 4 + i) * 512]);
      GLD_LDS16(ktb + cb + (w * 4 + i) * 512 + l * 8, &kTS[(w * 4 + i) * 512]);
    }
    if (w == 2) {
      GLD_LDS16(attf + ab + l * 8, &attS[0]);
      GLD_LDS16(attf + ab + 512 + l * 8, &attS[512]);
    }
    float u0 = ub[(rowbase + (t >> 4)) * 1024 + dbase + (t & 15)];
    float u1 = ub[(rowbase + 16 + (t >> 4)) * 1024 + dbase + (t & 15)];
    __syncthreads();

    // phase 1: partial w@S and q@S over this wave's K-slice (64 rows of S)
    floatx4 pw0, pw1, pq0, pq1;
    #pragma unroll
    for (int r = 0; r < 4; r++) { pw0[r] = 0.f; pw1[r] = 0.f; pq0[r] = 0.f; pq1[r] = 0.f; }
    #pragma unroll
    for (int s = 0; s < 2; s++) {
      const int koff = w * 2 + s;               // kstep 0..7
      bhalf8 sb = *(const bhalf8*)&SbT[col16 * 264 + koff * 32 + g * 8];
      bhalf8 wa0 = *(const bhalf8*)&wS[((koff * 2 + 0) * 64 + l) * 8];
      bhalf8 wa1 = *(const bhalf8*)&wS[((koff * 2 + 1) * 64 + l) * 8];
      bhalf8 qa0 = *(const bhalf8*)&qS[((koff * 2 + 0) * 64 + l) * 8];
      bhalf8 qa1 = *(const bhalf8*)&qS[((koff * 2 + 1) * 64 + l) * 8];
      pw0 = __builtin_amdgcn_mfma_f32_16x16x32_bf16(wa0, sb, pw0, 0, 0, 0);
      pw1 = __builtin_amdgcn_mfma_f32_16x16x32_bf16(wa1, sb, pw1, 0, 0, 0);
      pq0 = __builtin_amdgcn_mfma_f32_16x16x32_bf16(qa0, sb, pq0, 0, 0, 0);
      pq1 = __builtin_amdgcn_mfma_f32_16x16x32_bf16(qa1, sb, pq1, 0, 0, 0);
    }
    #pragma unroll
    for (int r = 0; r < 4; r++) {
      pbufW[w * 544 + (g * 4 + r) * 17 + col16] = pw0[r];
      pbufW[w * 544 + (16 + g * 4 + r) * 17 + col16] = pw1[r];
      pbufQ[w * 544 + (g * 4 + r) * 17 + col16] = pq0[r];
      pbufQ[w * 544 + (16 + g * 4 + r) * 17 + col16] = pq1[r];
    }
    __syncthreads();

    // phase 2: reduce partials -> ua (bf16, B-layout) and oacc = q@S
    {
      const int row = t >> 4, c2 = t & 15;
      const int i0 = row * 17 + c2, i1 = (row + 16) * 17 + c2;
      float wsA = pbufW[i0] + pbufW[544 + i0] + pbufW[1088 + i0] + pbufW[1632 + i0];
      float wsB = pbufW[i1] + pbufW[544 + i1] + pbufW[1088 + i1] + pbufW[1632 + i1];
      float qsA = pbufQ[i0] + pbufQ[544 + i0] + pbufQ[1088 + i0] + pbufQ[1632 + i0];
      float qsB = pbufQ[i1] + pbufQ[544 + i1] + pbufQ[1088 + i1] + pbufQ[1632 + i1];
      oacc[i0] = qsA;
      oacc[i1] = qsB;
      uaT[c2 * 40 + row] = f2bf(u0 - wsA);
      uaT[c2 * 40 + row + 16] = f2bf(u1 - wsB);
    }
    __syncthreads();

    // phase 3: S += k^T @ ua (MFMA accumulate); o = oacc + att@ua -> global
    bhalf8 uB = *(const bhalf8*)&uaT[col16 * 40 + g * 8];
    #pragma unroll
    for (int m = 0; m < 4; m++) {
      bhalf8 ka = *(const bhalf8*)&kTS[((w * 4 + m) * 64 + l) * 8];
      S_acc[m] = __builtin_amdgcn_mfma_f32_16x16x32_bf16(ka, uB, S_acc[m], 0, 0, 0);
    }
    if (w < 2) {
      floatx4 z;
      #pragma unroll
      for (int r = 0; r < 4; r++) z[r] = 0.f;
      bhalf8 aa = *(const bhalf8*)&attS[(w * 64 + l) * 8];
      floatx4 oat = __builtin_amdgcn_mfma_f32_16x16x32_bf16(aa, uB, z, 0, 0, 0);
      #pragma unroll
      for (int r = 0; r < 4; r++) {
        int row = w * 16 + g * 4 + r;
        float ov = oacc[row * 17 + col16] + oat[r];
        outb[(rowbase + row) * 1024 + dbase + col16] = f2bf(ov);
      }
    }
    __syncthreads();
  }
}

// ---------------------------------------------------------------------------
// logits (+)= hmidhalf @ W2half (20 cols). FIRST: init with b2.
// ---------------------------------------------------------------------------
template<int FIRST>
__global__ __launch_bounds__(256)
void logits_acc(const float* __restrict__ hmid, const float* __restrict__ W2,
                const float* __restrict__ b2, float* __restrict__ logits) {
  __shared__ float hrow[1024];
  __shared__ float part[8][20];
  int tok = blockIdx.x, t = threadIdx.x;
  ((float4*)hrow)[t] = ((const float4*)(hmid + (size_t)tok * 1024))[t];
  __syncthreads();
  if (t < 160) {
    int col = t % 20, seg = t / 20;
    float acc = 0.f;
    for (int kk = 0; kk < 128; kk++) {
      int k2 = seg * 128 + kk;
      acc += hrow[k2] * W2[(size_t)k2 * 20 + col];
    }
    part[seg][col] = acc;
  }
  __syncthreads();
  if (t < 20) {
    float s = 0.f;
    #pragma unroll
    for (int g = 0; g < 8; g++) s += part[g][t];
    if (FIRST) logits[(size_t)tok * 20 + t] = b2[t] + s;
    else       logits[(size_t)tok * 20 + t] += s;
  }
}

// ---------------------------------------------------------------------------
// probs = softmax(logits / tau) per (tok, head); one thread per (tok,h)
// ---------------------------------------------------------------------------
__global__ __launch_bounds__(256)
void softmax_probs(const float* __restrict__ logits, const float* __restrict__ ltau,
                   float* __restrict__ probs) {
  int idx = blockIdx.x * 256 + threadIdx.x;   // 32768
  int tok = idx >> 2, h = idx & 3;
  float tau = expf(ltau[h]);
  tau = tau < 0.5f ? 0.5f : tau;
  float x[5]; float m = -1e30f;
  #pragma unroll
  for (int i = 0; i < 5; i++) {
    x[i] = logits[(size_t)tok * 20 + h * 5 + i] / tau;
    m = fmaxf(m, x[i]);
  }
  float s = 0.f;
  #pragma unroll
  for (int i = 0; i < 5; i++) { x[i] = expf(x[i] - m); s += x[i]; }
  float inv = 1.f / s;
  #pragma unroll
  for (int i = 0; i < 5; i++) probs[(size_t)tok * 20 + h * 5 + i] = x[i] * inv;
}

// ---------------------------------------------------------------------------
// Mix 5 bf16 paths + f32 v with router probs + value gate, per-head RMSNorm,
// write bf16 omix. One wave per (tok, head).
// ---------------------------------------------------------------------------
__global__ __launch_bounds__(256)
void mix_rms(const ushort* __restrict__ f3, const ushort* __restrict__ f7,
             const ushort* __restrict__ f15, const ushort* __restrict__ f31,
             const ushort* __restrict__ dlt, const float* __restrict__ v,
             const float* __restrict__ probs, const float* __restrict__ pv,
             const float* __restrict__ onw, ushort* __restrict__ omix) {
  int tok = blockIdx.x;
  int h = threadIdx.x >> 6;
  int lane = threadIdx.x & 63;
  size_t base = (size_t)tok * 1024 + h * 256 + lane * 4;
  const float* pp = probs + (size_t)tok * 20 + h * 5;
  float p0 = pp[0], p1 = pp[1], p2 = pp[2], p3 = pp[3], p4 = pp[4];
  float pvv = pv[tok * 4 + h];
  float floor_tok = 0.01f + 0.09f * (1.f - pvv);
  float pa = (1.f - floor_tok) * pvv;
  float cm = 1.f - pa;
  ushort4 a4 = *(const ushort4*)&f3[base];
  ushort4 b4 = *(const ushort4*)&f7[base];
  ushort4 c4 = *(const ushort4*)&f15[base];
  ushort4 d4 = *(const ushort4*)&f31[base];
  ushort4 e4 = *(const ushort4*)&dlt[base];
  float4 vv = *(const float4*)&v[base];
  float av[4] = {bf2f(a4.x), bf2f(a4.y), bf2f(a4.z), bf2f(a4.w)};
  float bv[4] = {bf2f(b4.x), bf2f(b4.y), bf2f(b4.z), bf2f(b4.w)};
  float cv[4] = {bf2f(c4.x), bf2f(c4.y), bf2f(c4.z), bf2f(c4.w)};
  float dv[4] = {bf2f(d4.x), bf2f(d4.y), bf2f(d4.z), bf2f(d4.w)};
  float ev[4] = {bf2f(e4.x), bf2f(e4.y), bf2f(e4.z), bf2f(e4.w)};
  float vvv[4] = {vv.x, vv.y, vv.z, vv.w};
  float o[4];
  #pragma unroll
  for (int j = 0; j < 4; j++)
    o[j] = cm * (p0 * av[j] + p1 * bv[j] + p2 * cv[j] + p3 * dv[j] + p4 * ev[j]) +
           pa * vvv[j];
  float ss = o[0]*o[0] + o[1]*o[1] + o[2]*o[2] + o[3]*o[3];
  #pragma unroll
  for (int off = 32; off; off >>= 1) ss += __shfl_xor(ss, off);
  float sc = rsqrtf(ss * (1.f / 256.f) + 1e-5f);
  float4 wn = *(const float4*)&onw[lane * 4];
  ushort4 res;
  res.x = f2bf(o[0] * sc * wn.x); res.y = f2bf(o[1] * sc * wn.y);
  res.z = f2bf(o[2] * sc * wn.z); res.w = f2bf(o[3] * sc * wn.w);
  *(ushort4*)&omix[base] = res;
}

// ---------------------------------------------------------------------------
extern "C" void kernel_launch(void* const* d_in, const int* in_sizes, int n_in,
                              void* d_out, int out_size, void* d_ws, size_t ws_size,
                              hipStream_t stream) {
  const float* hs  = (const float*)d_in[0];
  const float* Wq  = (const float*)d_in[1];
  const float* Wk  = (const float*)d_in[2];
  const float* Wv  = (const float*)d_in[3];
  const float* qcw = (const float*)d_in[4];
  const float* kcw = (const float*)d_in[5];
  const float* vcw = (const float*)d_in[6];
  const float* Wb  = (const float*)d_in[7];
  const float* f3w = (const float*)d_in[8];
  const float* f7w = (const float*)d_in[9];
  const float* f15w= (const float*)d_in[10];
  const float* f31w= (const float*)d_in[11];
  const float* rW1 = (const float*)d_in[12];
  const float* rb1 = (const float*)d_in[13];
  const float* rW2 = (const float*)d_in[14];
  const float* rb2 = (const float*)d_in[15];
  const float* igW = (const float*)d_in[16];
  const float* igb = (const float*)d_in[17];
  const float* ltau= (const float*)d_in[18];
  const float* onw = (const float*)d_in[19];
  const float* Wo  = (const float*)d_in[20];
  float* out = (float*)d_out;
  float* ws  = (float*)d_ws;

  // f32 regions (floats from ws base); total ~241 MB (same as passing R2-R5)
  float* pre    = ws;              // phaseA scratch -> ktb+attf -> hmid
  float* qb     = ws +  8388608;   // q f32 -> W1T
  float* kb     = ws + 16777216;   // k f32 -> hs_bf2 + WoT
  float* vb     = ws + 25165824;   // v f32 (live to mix)
  float* ub     = ws + 33554432;   // phaseA bf16 staging -> u f32 -> f3b/f7b
  float* wbuf   = ws + 41943040;   // wfb+qfb -> f15b/f31b
  float* dlt    = ws + 50331648;   // dltb (bf16) + omixb (bf16)
  float* fwTp   = ws + 58720256;   // 57,344 floats (free ex-attb gap)
  float* beta   = ws + 59768832;
  float* pv     = ws + 59801600;
  float* logits = ws + 59834368;
  float* probs  = ws + 59998208;

  // bf16 aliases
  ushort* hs_bf1 = (ushort*)ub;
  ushort* WqT    = (ushort*)(ub + 4194304);
  ushort* WkT    = WqT + 1048576;
  ushort* WvT    = WkT + 1048576;
  ushort* ktb    = (ushort*)pre;                 // 1024*8192 us
  ushort* attfb  = (ushort*)(pre + 4194304);     // 1024*1024 us
  ushort* wfb    = (ushort*)wbuf;                // 1024*8192 us
  ushort* qfb    = (ushort*)(wbuf + 4194304);
  ushort* f3b    = (ushort*)ub;
  ushort* f7b    = (ushort*)(ub + 4194304);
  ushort* f15b   = (ushort*)wbuf;
  ushort* f31b   = (ushort*)(wbuf + 4194304);
  ushort* dltb   = (ushort*)dlt;
  ushort* omixb  = (ushort*)(dlt + 4194304);
  ushort* hs_bf2 = (ushort*)kb;
  ushort* WoT    = (ushort*)(kb + 4194304);
  ushort* W1T    = (ushort*)qb;
  float*  hmid   = pre;

  dim3 blk(256);
  dim3 gg(8, 64);      // 1024-N GEMM tiles

  // ---- phase A: q/k/v projections (bf16 MFMA) + conv + silu ----
  cvt_bf16<<<4096, blk, 0, stream>>>(hs, hs_bf1, 1048576);
  cvt_t<<<dim3(32, 32), blk, 0, stream>>>(Wq, WqT, 1024, 1024);
  cvt_t<<<dim3(32, 32), blk, 0, stream>>>(Wk, WkT, 1024, 1024);
  cvt_t<<<dim3(32, 32), blk, 0, stream>>>(Wv, WvT, 1024, 1024);
  gemm_bf<0><<<gg, blk, 0, stream>>>(hs_bf1, WqT, pre, 1024, 1024, 1024, 1024);
  conv4_silu<<<32768, blk, 0, stream>>>(pre, qcw, qb);
  gemm_bf<0><<<gg, blk, 0, stream>>>(hs_bf1, WkT, pre, 1024, 1024, 1024, 1024);
  conv4_silu<<<32768, blk, 0, stream>>>(pre, kcw, kb);
  gemm_bf<0><<<gg, blk, 0, stream>>>(hs_bf1, WvT, pre, 1024, 1024, 1024, 1024);
  conv4_silu<<<32768, blk, 0, stream>>>(pre, vcw, vb);

  beta_pv<<<8192, blk, 0, stream>>>(hs, Wb, igW, igb, beta, pv);
  l2norm_qk<<<8192, blk, 0, stream>>>(qb, kb);

  // ---- delta rule ----
  chunk_prep<<<1024, blk, 0, stream>>>(qb, kb, vb, beta, attfb, ub, wfb, qfb, ktb);
  delta_scan<<<256, blk, 0, stream>>>(wfb, qfb, ktb, attfb, ub, dltb);

  // ---- FIR paths: fused, transposed weights (bf16 out) ----
  pack_fir<<<224, blk, 0, stream>>>(f3w, f7w, f15w, f31w, fwTp);
  fir_all<<<32768, blk, 0, stream>>>(vb, fwTp, f3b, f7b, f15b, f31b);

  // ---- conversions for router ----
  cvt_bf16<<<4096, blk, 0, stream>>>(hs, hs_bf2, 1048576);
  cvt_t<<<dim3(64, 192), blk, 0, stream>>>(rW1, W1T, 6144, 2048);
  cvt_t<<<dim3(32, 32), blk, 0, stream>>>(Wo, WoT, 1024, 1024);

  // ---- router: two N-halves, each one fused virtual-K GEMM (+bias+gelu) ----
  APtrs ap;
  ap.p[0] = hs_bf2; ap.p[1] = f3b; ap.p[2] = f7b;
  ap.p[3] = f15b;   ap.p[4] = f31b; ap.p[5] = dltb;
  for (int nh = 0; nh < 2; nh++) {
    gemm_router<<<gg, blk, 0, stream>>>(ap, W1T + (size_t)nh * 1024 * 6144,
                                        rb1 + nh * 1024, hmid);
    if (nh == 0) logits_acc<1><<<8192, blk, 0, stream>>>(hmid, rW2, rb2, logits);
    else         logits_acc<0><<<8192, blk, 0, stream>>>(hmid, rW2 + (size_t)1024 * 20, rb2, logits);
  }
  softmax_probs<<<128, blk, 0, stream>>>(logits, ltau, probs);

  // ---- mix + RMSNorm (bf16 out) + output projection ----
  mix_rms<<<8192, blk, 0, stream>>>(f3b, f7b, f15b, f31b, dltb, vb, probs, pv,
                                    onw, omixb);
  gemm_bf<0><<<gg, blk, 0, stream>>>(omixb, WoT, out, 1024, 1024, 1024, 1024);
}

// Round 8
// 1223.652 us; speedup vs baseline: 1.1040x; 1.1040x over previous
//
#include <hip/hip_runtime.h>
#include <math.h>

// Problem constants (B=4, L=2048, D=1024, H=4, DK=DV=256, CHUNK=32)
#define NTOK   8192      // B*L
#define LSEQ   2048
#define NCHUNK 64        // L/32

typedef short bhalf8 __attribute__((ext_vector_type(8)));
typedef float floatx4 __attribute__((ext_vector_type(4)));

__device__ inline ushort f2bf(float f) {
  uint u = __float_as_uint(f);
  u += 0x7FFFu + ((u >> 16) & 1u);
  return (ushort)(u >> 16);
}
__device__ inline float bf2f(ushort h) {
  return __uint_as_float(((uint)h) << 16);
}

#define GLD_LDS16(g, s) __builtin_amdgcn_global_load_lds(                      \
    (const __attribute__((address_space(1))) void*)(g),                        \
    (__attribute__((address_space(3))) void*)(s), 16, 0, 0)

// ---------------------------------------------------------------------------
// f32 -> bf16 copy (n8 = elements/8)
// ---------------------------------------------------------------------------
__global__ __launch_bounds__(256)
void cvt_bf16(const float* __restrict__ x, ushort* __restrict__ y, int n8) {
  int i = blockIdx.x * 256 + threadIdx.x;
  if (i >= n8) return;
  const float4* xp = (const float4*)x;
  float4 a = xp[2 * i], b = xp[2 * i + 1];
  uint4 o;
  o.x = (uint)f2bf(a.x) | ((uint)f2bf(a.y) << 16);
  o.y = (uint)f2bf(a.z) | ((uint)f2bf(a.w) << 16);
  o.z = (uint)f2bf(b.x) | ((uint)f2bf(b.y) << 16);
  o.w = (uint)f2bf(b.z) | ((uint)f2bf(b.w) << 16);
  ((uint4*)y)[i] = o;
}

// ---------------------------------------------------------------------------
// f32 [R][C] -> bf16 [C][R] transpose (weights). Grid (C/32, R/32), 256 thr.
// ---------------------------------------------------------------------------
__global__ __launch_bounds__(256)
void cvt_t(const float* __restrict__ x, ushort* __restrict__ y, int R, int C) {
  __shared__ float tile[32][33];
  int r0 = blockIdx.y * 32, c0 = blockIdx.x * 32;
  int tr = threadIdx.x >> 5;       // 0..7
  int tc = threadIdx.x & 31;
  #pragma unroll
  for (int rr = tr; rr < 32; rr += 8)
    tile[rr][tc] = x[(size_t)(r0 + rr) * C + c0 + tc];
  __syncthreads();
  #pragma unroll
  for (int rr = tr; rr < 32; rr += 8)
    y[(size_t)(c0 + rr) * R + r0 + tc] = f2bf(tile[tc][rr]);
}

// ---------------------------------------------------------------------------
// bf16 MFMA GEMM: C[M,N] = (ACC? C:0) + A[M,K] @ BT[N,K]^T
// 128x128 tile, BK=32, 256 thr (4 waves 2x2), 4x4 frags of 16x16x32.
// XOR-swizzled LDS (rule #21, both-sides): staging keeps R5's coalesced quads
// (lane l -> row l>>2, colgrp (l&3)^((l>>3)&3) of a contiguous 64B segment);
// fragment read applies the same XOR -> 2-way banks (free, m136).
// ---------------------------------------------------------------------------
template<int ACC>
__global__ __launch_bounds__(256)
void gemm_bf(const ushort* __restrict__ A, const ushort* __restrict__ BT,
             float* __restrict__ C, int K, int lda, int ldbt, int ldc) {
  __shared__ ushort Asm[128 * 32];
  __shared__ ushort Bsm[128 * 32];
  const int t = threadIdx.x;
  const int w = t >> 6, l = t & 63;
  const int m0 = blockIdx.y * 128, n0 = blockIdx.x * 128;
  const int wr = w >> 1, wc = w & 1;
  const int srow = l >> 2;                    // staging row within subtile
  const int sgc  = (l & 3) ^ ((l >> 3) & 3);  // swizzled staging col-group
  // fragment read offset (ushort) within a subtile, lane-linear rows + XOR col
  const int ridx = (l & 15) * 32 + (((l >> 4) ^ ((l >> 1) & 3)) * 8);

  floatx4 acc[4][4];
  #pragma unroll
  for (int i = 0; i < 4; i++)
    #pragma unroll
    for (int j = 0; j < 4; j++)
      #pragma unroll
      for (int r = 0; r < 4; r++) acc[i][j][r] = 0.f;

  for (int k0 = 0; k0 < K; k0 += 32) {
    __syncthreads();
    #pragma unroll
    for (int j = 0; j < 2; j++) {
      int sub = w * 2 + j;             // subtile 0..7
      GLD_LDS16(A + (size_t)(m0 + sub * 16 + srow) * lda + k0 + sgc * 8,
                Asm + sub * 512);
      GLD_LDS16(BT + (size_t)(n0 + sub * 16 + srow) * ldbt + k0 + sgc * 8,
                Bsm + sub * 512);
    }
    __syncthreads();
    bhalf8 af[4], bf_[4];
    #pragma unroll
    for (int i = 0; i < 4; i++)
      af[i] = *(const bhalf8*)&Asm[(wr * 4 + i) * 512 + ridx];
    #pragma unroll
    for (int j = 0; j < 4; j++)
      bf_[j] = *(const bhalf8*)&Bsm[(wc * 4 + j) * 512 + ridx];
    #pragma unroll
    for (int i = 0; i < 4; i++)
      #pragma unroll
      for (int j = 0; j < 4; j++)
        acc[i][j] = __builtin_amdgcn_mfma_f32_16x16x32_bf16(af[i], bf_[j],
                                                            acc[i][j], 0, 0, 0);
  }
  const int crow = (l >> 4) * 4;
  const int ccol = l & 15;
  #pragma unroll
  for (int i = 0; i < 4; i++)
    #pragma unroll
    for (int j = 0; j < 4; j++) {
      float* cp = &C[(size_t)(m0 + wr * 64 + i * 16 + crow) * ldc +
                     n0 + wc * 64 + j * 16 + ccol];
      #pragma unroll
      for (int r = 0; r < 4; r++) {
        if (ACC) cp[(size_t)r * ldc] += acc[i][j][r];
        else     cp[(size_t)r * ldc]  = acc[i][j][r];
      }
    }
}

// ---------------------------------------------------------------------------
// Router GEMM: C[8192,1024] = gelu(sum_p A_p[8192,1024] @ W1T[1024,6144]^T
//                                   + b1half)   (bias+gelu fused epilogue)
// ---------------------------------------------------------------------------
struct APtrs { const ushort* p[6]; };

__global__ __launch_bounds__(256)
void gemm_router(APtrs ap, const ushort* __restrict__ BT,
                 const float* __restrict__ bias, float* __restrict__ C) {
  __shared__ ushort Asm[128 * 32];
  __shared__ ushort Bsm[128 * 32];
  const int t = threadIdx.x;
  const int w = t >> 6, l = t & 63;
  const int m0 = blockIdx.y * 128, n0 = blockIdx.x * 128;
  const int wr = w >> 1, wc = w & 1;
  const int srow = l >> 2;
  const int sgc  = (l & 3) ^ ((l >> 3) & 3);
  const int ridx = (l & 15) * 32 + (((l >> 4) ^ ((l >> 1) & 3)) * 8);

  floatx4 acc[4][4];
  #pragma unroll
  for (int i = 0; i < 4; i++)
    #pragma unroll
    for (int j = 0; j < 4; j++)
      #pragma unroll
      for (int r = 0; r < 4; r++) acc[i][j][r] = 0.f;

  for (int k0 = 0; k0 < 6144; k0 += 32) {
    const ushort* Abase = ap.p[k0 >> 10];
    const int kk = k0 & 1023;
    __syncthreads();
    #pragma unroll
    for (int j = 0; j < 2; j++) {
      int sub = w * 2 + j;
      GLD_LDS16(Abase + (size_t)(m0 + sub * 16 + srow) * 1024 + kk + sgc * 8,
                Asm + sub * 512);
      GLD_LDS16(BT + (size_t)(n0 + sub * 16 + srow) * 6144 + k0 + sgc * 8,
                Bsm + sub * 512);
    }
    __syncthreads();
    bhalf8 af[4], bf_[4];
    #pragma unroll
    for (int i = 0; i < 4; i++)
      af[i] = *(const bhalf8*)&Asm[(wr * 4 + i) * 512 + ridx];
    #pragma unroll
    for (int j = 0; j < 4; j++)
      bf_[j] = *(const bhalf8*)&Bsm[(wc * 4 + j) * 512 + ridx];
    #pragma unroll
    for (int i = 0; i < 4; i++)
      #pragma unroll
      for (int j = 0; j < 4; j++)
        acc[i][j] = __builtin_amdgcn_mfma_f32_16x16x32_bf16(af[i], bf_[j],
                                                            acc[i][j], 0, 0, 0);
  }
  const int crow = (l >> 4) * 4;
  const int ccol = l & 15;
  #pragma unroll
  for (int i = 0; i < 4; i++)
    #pragma unroll
    for (int j = 0; j < 4; j++) {
      const int col = n0 + wc * 64 + j * 16 + ccol;
      const float bb = bias[col];
      float* cp = &C[(size_t)(m0 + wr * 64 + i * 16 + crow) * 1024 + col];
      #pragma unroll
      for (int r = 0; r < 4; r++) {
        float x = acc[i][j][r] + bb;
        cp[(size_t)r * 1024] = 0.5f * x * (1.f + erff(x * 0.70710678118654752f));
      }
    }
}

// ---------------------------------------------------------------------------
// Causal depthwise conv (K=4) + SiLU.  x,y: (B*L, 1024) f32.
// ---------------------------------------------------------------------------
__global__ __launch_bounds__(256)
void conv4_silu(const float* __restrict__ x, const float* __restrict__ w,
                float* __restrict__ y) {
  int idx = blockIdx.x * 256 + threadIdx.x;
  int c = idx & 1023;
  int bl = idx >> 10;
  int l = bl & (LSEQ - 1);
  float w0 = w[c * 4 + 0], w1 = w[c * 4 + 1], w2 = w[c * 4 + 2], w3 = w[c * 4 + 3];
  float acc = x[idx] * w3;
  if (l >= 1) acc += x[idx - 1024] * w2;
  if (l >= 2) acc += x[idx - 2048] * w1;
  if (l >= 3) acc += x[idx - 3072] * w0;
  y[idx] = acc / (1.f + expf(-acc));
}

// ---------------------------------------------------------------------------
// Pack FIR weights transposed: fwTp[row][c], rows 0..2=f3(j), 3..9=f7(j),
// 10..24=f15(j), 25..55=f31(j).
// ---------------------------------------------------------------------------
__global__ __launch_bounds__(256)
void pack_fir(const float* __restrict__ f3w, const float* __restrict__ f7w,
              const float* __restrict__ f15w, const float* __restrict__ f31w,
              float* __restrict__ fwTp) {
  int i = blockIdx.x * 256 + threadIdx.x;   // 56*1024
  if (i >= 57344) return;
  int row = i >> 10, c = i & 1023;
  float val;
  if (row < 3)       val = f3w[c * 3 + row];
  else if (row < 10) val = f7w[c * 7 + (row - 3)];
  else if (row < 25) val = f15w[c * 15 + (row - 10)];
  else               val = f31w[c * 31 + (row - 25)];
  fwTp[i] = val;
}

// ---------------------------------------------------------------------------
// All 4 depthwise causal FIRs in one pass. bf16 outputs.
// ---------------------------------------------------------------------------
__global__ __launch_bounds__(256)
void fir_all(const float* __restrict__ v, const float* __restrict__ fwTp,
             ushort* __restrict__ y3, ushort* __restrict__ y7,
             ushort* __restrict__ y15, ushort* __restrict__ y31) {
  int idx = blockIdx.x * 256 + threadIdx.x;   // over 8192*1024
  int c = idx & 1023;
  int l = (idx >> 10) & (LSEQ - 1);
  float a3 = 0.f, a7 = 0.f, a15 = 0.f, a31 = 0.f;
  #pragma unroll
  for (int back = 30; back >= 0; back--) {
    float x = (l >= back) ? v[idx - back * 1024] : 0.f;
    a31 += x * fwTp[(25 + 30 - back) * 1024 + c];
    if (back <= 14) a15 += x * fwTp[(10 + 14 - back) * 1024 + c];
    if (back <= 6)  a7  += x * fwTp[(3 + 6 - back) * 1024 + c];
    if (back <= 2)  a3  += x * fwTp[(2 - back) * 1024 + c];
  }
  y3[idx]  = f2bf(a3);
  y7[idx]  = f2bf(a7);
  y15[idx] = f2bf(a15);
  y31[idx] = f2bf(a31);
}

// ---------------------------------------------------------------------------
// beta = sigmoid(hs@Wb), p_value = sigmoid(hs@idW + idb); one wave per (tok,h)
// ---------------------------------------------------------------------------
__global__ __launch_bounds__(256)
void beta_pv(const float* __restrict__ hs, const float* __restrict__ Wb,
             const float* __restrict__ idW, const float* __restrict__ idb,
             float* __restrict__ beta, float* __restrict__ pv) {
  int tok = blockIdx.x;
  int h = threadIdx.x >> 6;
  int lane = threadIdx.x & 63;
  const float* hrow = hs + (size_t)tok * 1024;
  float s1 = 0.f, s2 = 0.f;
  #pragma unroll
  for (int j = 0; j < 16; j++) {
    int d = lane + j * 64;
    float hv = hrow[d];
    s1 += hv * Wb[d * 4 + h];
    s2 += hv * idW[d * 4 + h];
  }
  #pragma unroll
  for (int off = 32; off; off >>= 1) {
    s1 += __shfl_down(s1, off);
    s2 += __shfl_down(s2, off);
  }
  if (lane == 0) {
    beta[tok * 4 + h] = 1.f / (1.f + expf(-s1));
    pv[tok * 4 + h] = 1.f / (1.f + expf(-(s2 + idb[h])));
  }
}

// ---------------------------------------------------------------------------
// In-place l2norm of q and k per (tok, head) over 256 dims. Wave per (tok,h).
// ---------------------------------------------------------------------------
__global__ __launch_bounds__(256)
void l2norm_qk(float* __restrict__ q, float* __restrict__ k) {
  int tok = blockIdx.x;
  int h = threadIdx.x >> 6;
  int lane = threadIdx.x & 63;
  size_t base = (size_t)tok * 1024 + h * 256 + lane * 4;
  {
    float4* p = (float4*)(q + base);
    float4 v = *p;
    float ss = v.x * v.x + v.y * v.y + v.z * v.z + v.w * v.w;
    #pragma unroll
    for (int off = 32; off; off >>= 1) ss += __shfl_xor(ss, off);
    float sc = rsqrtf(ss + 1e-6f);
    v.x *= sc; v.y *= sc; v.z *= sc; v.w *= sc;
    *p = v;
  }
  {
    float4* p = (float4*)(k + base);
    float4 v = *p;
    float ss = v.x * v.x + v.y * v.y + v.z * v.z + v.w * v.w;
    #pragma unroll
    for (int off = 32; off; off >>= 1) ss += __shfl_xor(ss, off);
    float sc = rsqrtf(ss + 1e-6f);
    v.x *= sc; v.y *= sc; v.z *= sc; v.w *= sc;
    *p = v;
  }
}

// ---------------------------------------------------------------------------
// Per-(b,h,chunk): att = tril(q k^T) [bf16 frag-order], forward substitution
// u = T^{-1}(v*beta) [f32], w = T^{-1}(k*beta) [bf16 frag-order],
// q and k^T [bf16 frag-order] for the MFMA scan.
// ---------------------------------------------------------------------------
__global__ __launch_bounds__(256)
void chunk_prep(const float* __restrict__ q, const float* __restrict__ k,
                const float* __restrict__ v, const float* __restrict__ beta,
                ushort* __restrict__ attf, float* __restrict__ ub,
                ushort* __restrict__ wfb, ushort* __restrict__ qfb,
                ushort* __restrict__ ktb) {
  __shared__ float kbuf[32 * 260];
  __shared__ float qbuf[32 * 260];
  __shared__ float Am[32 * 32];
  __shared__ float bet[32];
  const int t = threadIdx.x;
  const int blk = blockIdx.x;          // ((b*4+h)*64 + n)
  const int n = blk & 63, bh = blk >> 6;
  const int h = bh & 3, b = bh >> 2;
  const size_t rowbase = (size_t)b * LSEQ + n * 32;
  const int cbase = h * 256;
  const int srow = t >> 6, scol = (t & 63) * 4;
  const size_t fb = (size_t)blk * 8192;   // frag-buffer base (ushort)

  #pragma unroll
  for (int rep = 0; rep < 8; rep++) {
    int r = rep * 4 + srow;
    *(float4*)&kbuf[r * 260 + scol] =
        *(const float4*)&k[(rowbase + r) * 1024 + cbase + scol];
    *(float4*)&qbuf[r * 260 + scol] =
        *(const float4*)&q[(rowbase + r) * 1024 + cbase + scol];
  }
  if (t < 32) bet[t] = beta[(rowbase + t) * 4 + h];
  __syncthreads();

  // att (bf16 frag order) + A
  #pragma unroll
  for (int e = 0; e < 4; e++) {
    int idx = t + e * 256;
    int i = idx >> 5, jc = idx & 31;
    float da = 0.f, dq = 0.f;
    for (int d0 = 0; d0 < 256; d0 += 4) {
      float4 kj = *(float4*)&kbuf[jc * 260 + d0];
      float4 ki = *(float4*)&kbuf[i * 260 + d0];
      float4 qi = *(float4*)&qbuf[i * 260 + d0];
      da += ki.x * kj.x + ki.y * kj.y + ki.z * kj.z + ki.w * kj.w;
      dq += qi.x * kj.x + qi.y * kj.y + qi.z * kj.z + qi.w * kj.w;
    }
    Am[i * 32 + jc] = (jc < i) ? bet[i] * da : 0.f;
    float av = (jc <= i) ? dq : 0.f;
    attf[(size_t)blk * 1024 + (i >> 4) * 512 +
         ((i & 15) + ((jc >> 3) & 3) * 16) * 8 + (jc & 7)] = f2bf(av);
  }
  __syncthreads();

  // k^T frag writes (A-operand, M=dk 256, K=c 32), pre-substitution.
  #pragma unroll
  for (int cg = 0; cg < 4; cg++) {
    bhalf8 pk;
    #pragma unroll
    for (int j = 0; j < 8; j++)
      pk[j] = (short)f2bf(kbuf[(cg * 8 + j) * 260 + t]);
    *(bhalf8*)&ktb[fb + (t >> 4) * 512 + ((t & 15) + cg * 16) * 8] = pk;
  }

  // k -> w in place (thread owns column t; column-private)
  #pragma unroll 1
  for (int i = 0; i < 32; i++) {
    float val = bet[i] * kbuf[i * 260 + t];
    for (int j = 0; j < i; j++) val -= Am[i * 32 + j] * kbuf[j * 260 + t];
    kbuf[i * 260 + t] = val;
  }
  __syncthreads();   // w stable for cross-column repack

  // w and q frag repack: pack p -> (c = p&31, dk8 = p>>5)
  #pragma unroll
  for (int rep = 0; rep < 4; rep++) {
    int p = rep * 256 + t;
    int c = p & 31, dk8 = p >> 5;
    size_t pos = fb + ((size_t)(dk8 >> 2) * 2 + (c >> 4)) * 512 +
                 ((c & 15) + (dk8 & 3) * 16) * 8;
    bhalf8 pw, pq;
    #pragma unroll
    for (int j = 0; j < 8; j++) {
      pw[j] = (short)f2bf(kbuf[c * 260 + dk8 * 8 + j]);
      pq[j] = (short)f2bf(qbuf[c * 260 + dk8 * 8 + j]);
    }
    *(bhalf8*)&wfb[pos] = pw;
    *(bhalf8*)&qfb[pos] = pq;
  }
  __syncthreads();

  // v into qbuf, then v -> u (f32)
  #pragma unroll
  for (int rep = 0; rep < 8; rep++) {
    int r = rep * 4 + srow;
    *(float4*)&qbuf[r * 260 + scol] =
        *(const float4*)&v[(rowbase + r) * 1024 + cbase + scol];
  }
  __syncthreads();
  #pragma unroll 1
  for (int i = 0; i < 32; i++) {
    float val = bet[i] * qbuf[i * 260 + t];
    for (int j = 0; j < i; j++) val -= Am[i * 32 + j] * qbuf[j * 260 + t];
    qbuf[i * 260 + t] = val;
  }
  for (int j = 0; j < 32; j++)
    ub[(rowbase + j) * 1024 + cbase + t] = qbuf[j * 260 + t];
}

// ---------------------------------------------------------------------------
// MFMA delta scan. Block per (b,h,dv-slice of 16): 256 blocks, 4 waves.
// S (256x16) lives as f32 MFMA accumulators (4 frags/wave, K-split by wave).
// ---------------------------------------------------------------------------
__global__ __launch_bounds__(256)
void delta_scan(const ushort* __restrict__ wfb, const ushort* __restrict__ qfb,
                const ushort* __restrict__ ktb, const ushort* __restrict__ attf,
                const float* __restrict__ ub, ushort* __restrict__ outb) {
  __shared__ ushort wS[8192];
  __shared__ ushort qS[8192];
  __shared__ ushort kTS[8192];
  __shared__ ushort attS[1024];
  __shared__ ushort SbT[16 * 264];
  __shared__ ushort uaT[16 * 40];
  __shared__ float pbufW[4 * 544];
  __shared__ float pbufQ[4 * 544];
  __shared__ float oacc[544];
  const int t = threadIdx.x;
  const int w = t >> 6, l = t & 63;
  const int col16 = l & 15, g = l >> 4;
  const int blk = blockIdx.x;
  const int dsl = blk & 15, bh = blk >> 4;
  const int h = bh & 3, b = bh >> 2;
  const int dbase = h * 256 + dsl * 16;

  floatx4 S_acc[4];
  #pragma unroll
  for (int m = 0; m < 4; m++)
    #pragma unroll
    for (int r = 0; r < 4; r++) S_acc[m][r] = 0.f;

  for (int n = 0; n < NCHUNK; n++) {
    const size_t cb = ((size_t)(bh * 64 + n)) * 8192;
    const size_t ab = ((size_t)(bh * 64 + n)) * 1024;
    const size_t rowbase = (size_t)b * LSEQ + n * 32;

    // SbT <- bf16(S_acc): lane holds rows w*64+m*16+g*4+{0..3}, col col16
    #pragma unroll
    for (int m = 0; m < 4; m++) {
      uint lo = (uint)f2bf(S_acc[m][0]) | ((uint)f2bf(S_acc[m][1]) << 16);
      uint hi = (uint)f2bf(S_acc[m][2]) | ((uint)f2bf(S_acc[m][3]) << 16);
      uint2 pk; pk.x = lo; pk.y = hi;
      *(uint2*)&SbT[col16 * 264 + w * 64 + m * 16 + g * 4] = pk;
    }
    // stage w/q/kT (16 KB each) + att (2 KB) via global_load_lds
    #pragma unroll
    for (int i = 0; i < 4; i++) {
      GLD_LDS16(wfb + cb + (w * 4 + i) * 512 + l * 8, &wS[(w * 4 + i) * 512]);
      GLD_LDS16(qfb + cb + (w * 4 + i) * 512 + l * 8, &qS[(w * 4 + i) * 512]);
      GLD_LDS16(ktb + cb + (w * 4 + i) * 512 + l * 8, &kTS[(w * 4 + i) * 512]);
    }
    if (w == 2) {
      GLD_LDS16(attf + ab + l * 8, &attS[0]);
      GLD_LDS16(attf + ab + 512 + l * 8, &attS[512]);
    }
    float u0 = ub[(rowbase + (t >> 4)) * 1024 + dbase + (t & 15)];
    float u1 = ub[(rowbase + 16 + (t >> 4)) * 1024 + dbase + (t & 15)];
    __syncthreads();

    // phase 1: partial w@S and q@S over this wave's K-slice (64 rows of S)
    floatx4 pw0, pw1, pq0, pq1;
    #pragma unroll
    for (int r = 0; r < 4; r++) { pw0[r] = 0.f; pw1[r] = 0.f; pq0[r] = 0.f; pq1[r] = 0.f; }
    #pragma unroll
    for (int s = 0; s < 2; s++) {
      const int koff = w * 2 + s;               // kstep 0..7
      bhalf8 sb = *(const bhalf8*)&SbT[col16 * 264 + koff * 32 + g * 8];
      bhalf8 wa0 = *(const bhalf8*)&wS[((koff * 2 + 0) * 64 + l) * 8];
      bhalf8 wa1 = *(const bhalf8*)&wS[((koff * 2 + 1) * 64 + l) * 8];
      bhalf8 qa0 = *(const bhalf8*)&qS[((koff * 2 + 0) * 64 + l) * 8];
      bhalf8 qa1 = *(const bhalf8*)&qS[((koff * 2 + 1) * 64 + l) * 8];
      pw0 = __builtin_amdgcn_mfma_f32_16x16x32_bf16(wa0, sb, pw0, 0, 0, 0);
      pw1 = __builtin_amdgcn_mfma_f32_16x16x32_bf16(wa1, sb, pw1, 0, 0, 0);
      pq0 = __builtin_amdgcn_mfma_f32_16x16x32_bf16(qa0, sb, pq0, 0, 0, 0);
      pq1 = __builtin_amdgcn_mfma_f32_16x16x32_bf16(qa1, sb, pq1, 0, 0, 0);
    }
    #pragma unroll
    for (int r = 0; r < 4; r++) {
      pbufW[w * 544 + (g * 4 + r) * 17 + col16] = pw0[r];
      pbufW[w * 544 + (16 + g * 4 + r) * 17 + col16] = pw1[r];
      pbufQ[w * 544 + (g * 4 + r) * 17 + col16] = pq0[r];
      pbufQ[w * 544 + (16 + g * 4 + r) * 17 + col16] = pq1[r];
    }
    __syncthreads();

    // phase 2: reduce partials -> ua (bf16, B-layout) and oacc = q@S
    {
      const int row = t >> 4, c2 = t & 15;
      const int i0 = row * 17 + c2, i1 = (row + 16) * 17 + c2;
      float wsA = pbufW[i0] + pbufW[544 + i0] + pbufW[1088 + i0] + pbufW[1632 + i0];
      float wsB = pbufW[i1] + pbufW[544 + i1] + pbufW[1088 + i1] + pbufW[1632 + i1];
      float qsA = pbufQ[i0] + pbufQ[544 + i0] + pbufQ[1088 + i0] + pbufQ[1632 + i0];
      float qsB = pbufQ[i1] + pbufQ[544 + i1] + pbufQ[1088 + i1] + pbufQ[1632 + i1];
      oacc[i0] = qsA;
      oacc[i1] = qsB;
      uaT[c2 * 40 + row] = f2bf(u0 - wsA);
      uaT[c2 * 40 + row + 16] = f2bf(u1 - wsB);
    }
    __syncthreads();

    // phase 3: S += k^T @ ua (MFMA accumulate); o = oacc + att@ua -> global
    bhalf8 uB = *(const bhalf8*)&uaT[col16 * 40 + g * 8];
    #pragma unroll
    for (int m = 0; m < 4; m++) {
      bhalf8 ka = *(const bhalf8*)&kTS[((w * 4 + m) * 64 + l) * 8];
      S_acc[m] = __builtin_amdgcn_mfma_f32_16x16x32_bf16(ka, uB, S_acc[m], 0, 0, 0);
    }
    if (w < 2) {
      floatx4 z;
      #pragma unroll
      for (int r = 0; r < 4; r++) z[r] = 0.f;
      bhalf8 aa = *(const bhalf8*)&attS[(w * 64 + l) * 8];
      floatx4 oat = __builtin_amdgcn_mfma_f32_16x16x32_bf16(aa, uB, z, 0, 0, 0);
      #pragma unroll
      for (int r = 0; r < 4; r++) {
        int row = w * 16 + g * 4 + r;
        float ov = oacc[row * 17 + col16] + oat[r];
        outb[(rowbase + row) * 1024 + dbase + col16] = f2bf(ov);
      }
    }
    __syncthreads();
  }
}

// ---------------------------------------------------------------------------
// logits (+)= hmidhalf @ W2half (20 cols). FIRST: init with b2.
// ---------------------------------------------------------------------------
template<int FIRST>
__global__ __launch_bounds__(256)
void logits_acc(const float* __restrict__ hmid, const float* __restrict__ W2,
                const float* __restrict__ b2, float* __restrict__ logits) {
  __shared__ float hrow[1024];
  __shared__ float part[8][20];
  int tok = blockIdx.x, t = threadIdx.x;
  ((float4*)hrow)[t] = ((const float4*)(hmid + (size_t)tok * 1024))[t];
  __syncthreads();
  if (t < 160) {
    int col = t % 20, seg = t / 20;
    float acc = 0.f;
    for (int kk = 0; kk < 128; kk++) {
      int k2 = seg * 128 + kk;
      acc += hrow[k2] * W2[(size_t)k2 * 20 + col];
    }
    part[seg][col] = acc;
  }
  __syncthreads();
  if (t < 20) {
    float s = 0.f;
    #pragma unroll
    for (int g = 0; g < 8; g++) s += part[g][t];
    if (FIRST) logits[(size_t)tok * 20 + t] = b2[t] + s;
    else       logits[(size_t)tok * 20 + t] += s;
  }
}

// ---------------------------------------------------------------------------
// probs = softmax(logits / tau) per (tok, head); one thread per (tok,h)
// ---------------------------------------------------------------------------
__global__ __launch_bounds__(256)
void softmax_probs(const float* __restrict__ logits, const float* __restrict__ ltau,
                   float* __restrict__ probs) {
  int idx = blockIdx.x * 256 + threadIdx.x;   // 32768
  int tok = idx >> 2, h = idx & 3;
  float tau = expf(ltau[h]);
  tau = tau < 0.5f ? 0.5f : tau;
  float x[5]; float m = -1e30f;
  #pragma unroll
  for (int i = 0; i < 5; i++) {
    x[i] = logits[(size_t)tok * 20 + h * 5 + i] / tau;
    m = fmaxf(m, x[i]);
  }
  float s = 0.f;
  #pragma unroll
  for (int i = 0; i < 5; i++) { x[i] = expf(x[i] - m); s += x[i]; }
  float inv = 1.f / s;
  #pragma unroll
  for (int i = 0; i < 5; i++) probs[(size_t)tok * 20 + h * 5 + i] = x[i] * inv;
}

// ---------------------------------------------------------------------------
// Mix 5 bf16 paths + f32 v with router probs + value gate, per-head RMSNorm,
// write bf16 omix. One wave per (tok, head).
// ---------------------------------------------------------------------------
__global__ __launch_bounds__(256)
void mix_rms(const ushort* __restrict__ f3, const ushort* __restrict__ f7,
             const ushort* __restrict__ f15, const ushort* __restrict__ f31,
             const ushort* __restrict__ dlt, const float* __restrict__ v,
             const float* __restrict__ probs, const float* __restrict__ pv,
             const float* __restrict__ onw, ushort* __restrict__ omix) {
  int tok = blockIdx.x;
  int h = threadIdx.x >> 6;
  int lane = threadIdx.x & 63;
  size_t base = (size_t)tok * 1024 + h * 256 + lane * 4;
  const float* pp = probs + (size_t)tok * 20 + h * 5;
  float p0 = pp[0], p1 = pp[1], p2 = pp[2], p3 = pp[3], p4 = pp[4];
  float pvv = pv[tok * 4 + h];
  float floor_tok = 0.01f + 0.09f * (1.f - pvv);
  float pa = (1.f - floor_tok) * pvv;
  float cm = 1.f - pa;
  ushort4 a4 = *(const ushort4*)&f3[base];
  ushort4 b4 = *(const ushort4*)&f7[base];
  ushort4 c4 = *(const ushort4*)&f15[base];
  ushort4 d4 = *(const ushort4*)&f31[base];
  ushort4 e4 = *(const ushort4*)&dlt[base];
  float4 vv = *(const float4*)&v[base];
  float av[4] = {bf2f(a4.x), bf2f(a4.y), bf2f(a4.z), bf2f(a4.w)};
  float bv[4] = {bf2f(b4.x), bf2f(b4.y), bf2f(b4.z), bf2f(b4.w)};
  float cv[4] = {bf2f(c4.x), bf2f(c4.y), bf2f(c4.z), bf2f(c4.w)};
  float dv[4] = {bf2f(d4.x), bf2f(d4.y), bf2f(d4.z), bf2f(d4.w)};
  float ev[4] = {bf2f(e4.x), bf2f(e4.y), bf2f(e4.z), bf2f(e4.w)};
  float vvv[4] = {vv.x, vv.y, vv.z, vv.w};
  float o[4];
  #pragma unroll
  for (int j = 0; j < 4; j++)
    o[j] = cm * (p0 * av[j] + p1 * bv[j] + p2 * cv[j] + p3 * dv[j] + p4 * ev[j]) +
           pa * vvv[j];
  float ss = o[0]*o[0] + o[1]*o[1] + o[2]*o[2] + o[3]*o[3];
  #pragma unroll
  for (int off = 32; off; off >>= 1) ss += __shfl_xor(ss, off);
  float sc = rsqrtf(ss * (1.f / 256.f) + 1e-5f);
  float4 wn = *(const float4*)&onw[lane * 4];
  ushort4 res;
  res.x = f2bf(o[0] * sc * wn.x); res.y = f2bf(o[1] * sc * wn.y);
  res.z = f2bf(o[2] * sc * wn.z); res.w = f2bf(o[3] * sc * wn.w);
  *(ushort4*)&omix[base] = res;
}

// ---------------------------------------------------------------------------
extern "C" void kernel_launch(void* const* d_in, const int* in_sizes, int n_in,
                              void* d_out, int out_size, void* d_ws, size_t ws_size,
                              hipStream_t stream) {
  const float* hs  = (const float*)d_in[0];
  const float* Wq  = (const float*)d_in[1];
  const float* Wk  = (const float*)d_in[2];
  const float* Wv  = (const float*)d_in[3];
  const float* qcw = (const float*)d_in[4];
  const float* kcw = (const float*)d_in[5];
  const float* vcw = (const float*)d_in[6];
  const float* Wb  = (const float*)d_in[7];
  const float* f3w = (const float*)d_in[8];
  const float* f7w = (const float*)d_in[9];
  const float* f15w= (const float*)d_in[10];
  const float* f31w= (const float*)d_in[11];
  const float* rW1 = (const float*)d_in[12];
  const float* rb1 = (const float*)d_in[13];
  const float* rW2 = (const float*)d_in[14];
  const float* rb2 = (const float*)d_in[15];
  const float* igW = (const float*)d_in[16];
  const float* igb = (const float*)d_in[17];
  const float* ltau= (const float*)d_in[18];
  const float* onw = (const float*)d_in[19];
  const float* Wo  = (const float*)d_in[20];
  float* out = (float*)d_out;
  float* ws  = (float*)d_ws;

  // f32 regions (floats from ws base); total ~241 MB (same as passing R2-R7)
  float* pre    = ws;              // phaseA scratch -> ktb+attf -> hmid
  float* qb     = ws +  8388608;   // q f32 -> W1T
  float* kb     = ws + 16777216;   // k f32 -> hs_bf2 + WoT
  float* vb     = ws + 25165824;   // v f32 (live to mix)
  float* ub     = ws + 33554432;   // phaseA bf16 staging -> u f32 -> f3b/f7b
  float* wbuf   = ws + 41943040;   // wfb+qfb -> f15b/f31b
  float* dlt    = ws + 50331648;   // dltb (bf16) + omixb (bf16)
  float* fwTp   = ws + 58720256;   // 57,344 floats (free ex-attb gap)
  float* beta   = ws + 59768832;
  float* pv     = ws + 59801600;
  float* logits = ws + 59834368;
  float* probs  = ws + 59998208;

  // bf16 aliases
  ushort* hs_bf1 = (ushort*)ub;
  ushort* WqT    = (ushort*)(ub + 4194304);
  ushort* WkT    = WqT + 1048576;
  ushort* WvT    = WkT + 1048576;
  ushort* ktb    = (ushort*)pre;                 // 1024*8192 us
  ushort* attfb  = (ushort*)(pre + 4194304);     // 1024*1024 us
  ushort* wfb    = (ushort*)wbuf;                // 1024*8192 us
  ushort* qfb    = (ushort*)(wbuf + 4194304);
  ushort* f3b    = (ushort*)ub;
  ushort* f7b    = (ushort*)(ub + 4194304);
  ushort* f15b   = (ushort*)wbuf;
  ushort* f31b   = (ushort*)(wbuf + 4194304);
  ushort* dltb   = (ushort*)dlt;
  ushort* omixb  = (ushort*)(dlt + 4194304);
  ushort* hs_bf2 = (ushort*)kb;
  ushort* WoT    = (ushort*)(kb + 4194304);
  ushort* W1T    = (ushort*)qb;
  float*  hmid   = pre;

  dim3 blk(256);
  dim3 gg(8, 64);      // 1024-N GEMM tiles

  // ---- phase A: q/k/v projections (bf16 MFMA) + conv + silu ----
  cvt_bf16<<<4096, blk, 0, stream>>>(hs, hs_bf1, 1048576);
  cvt_t<<<dim3(32, 32), blk, 0, stream>>>(Wq, WqT, 1024, 1024);
  cvt_t<<<dim3(32, 32), blk, 0, stream>>>(Wk, WkT, 1024, 1024);
  cvt_t<<<dim3(32, 32), blk, 0, stream>>>(Wv, WvT, 1024, 1024);
  gemm_bf<0><<<gg, blk, 0, stream>>>(hs_bf1, WqT, pre, 1024, 1024, 1024, 1024);
  conv4_silu<<<32768, blk, 0, stream>>>(pre, qcw, qb);
  gemm_bf<0><<<gg, blk, 0, stream>>>(hs_bf1, WkT, pre, 1024, 1024, 1024, 1024);
  conv4_silu<<<32768, blk, 0, stream>>>(pre, kcw, kb);
  gemm_bf<0><<<gg, blk, 0, stream>>>(hs_bf1, WvT, pre, 1024, 1024, 1024, 1024);
  conv4_silu<<<32768, blk, 0, stream>>>(pre, vcw, vb);

  beta_pv<<<8192, blk, 0, stream>>>(hs, Wb, igW, igb, beta, pv);
  l2norm_qk<<<8192, blk, 0, stream>>>(qb, kb);

  // ---- delta rule ----
  chunk_prep<<<1024, blk, 0, stream>>>(qb, kb, vb, beta, attfb, ub, wfb, qfb, ktb);
  delta_scan<<<256, blk, 0, stream>>>(wfb, qfb, ktb, attfb, ub, dltb);

  // ---- FIR paths: fused, transposed weights (bf16 out) ----
  pack_fir<<<224, blk, 0, stream>>>(f3w, f7w, f15w, f31w, fwTp);
  fir_all<<<32768, blk, 0, stream>>>(vb, fwTp, f3b, f7b, f15b, f31b);

  // ---- conversions for router ----
  cvt_bf16<<<4096, blk, 0, stream>>>(hs, hs_bf2, 1048576);
  cvt_t<<<dim3(64, 192), blk, 0, stream>>>(rW1, W1T, 6144, 2048);
  cvt_t<<<dim3(32, 32), blk, 0, stream>>>(Wo, WoT, 1024, 1024);

  // ---- router: two N-halves, each one fused virtual-K GEMM (+bias+gelu) ----
  APtrs ap;
  ap.p[0] = hs_bf2; ap.p[1] = f3b; ap.p[2] = f7b;
  ap.p[3] = f15b;   ap.p[4] = f31b; ap.p[5] = dltb;
  for (int nh = 0; nh < 2; nh++) {
    gemm_router<<<gg, blk, 0, stream>>>(ap, W1T + (size_t)nh * 1024 * 6144,
                                        rb1 + nh * 1024, hmid);
    if (nh == 0) logits_acc<1><<<8192, blk, 0, stream>>>(hmid, rW2, rb2, logits);
    else         logits_acc<0><<<8192, blk, 0, stream>>>(hmid, rW2 + (size_t)1024 * 20, rb2, logits);
  }
  softmax_probs<<<128, blk, 0, stream>>>(logits, ltau, probs);

  // ---- mix + RMSNorm (bf16 out) + output projection ----
  mix_rms<<<8192, blk, 0, stream>>>(f3b, f7b, f15b, f31b, dltb, vb, probs, pv,
                                    onw, omixb);
  gemm_bf<0><<<gg, blk, 0, stream>>>(omixb, WoT, out, 1024, 1024, 1024, 1024);
}

// Round 9
// 1199.280 us; speedup vs baseline: 1.1265x; 1.0203x over previous
//
#include <hip/hip_runtime.h>
#include <math.h>

// Problem constants (B=4, L=2048, D=1024, H=4, DK=DV=256, CHUNK=32)
#define NTOK   8192      // B*L
#define LSEQ   2048
#define NCHUNK 64        // L/32

typedef short bhalf8 __attribute__((ext_vector_type(8)));
typedef float floatx4 __attribute__((ext_vector_type(4)));

__device__ inline ushort f2bf(float f) {
  uint u = __float_as_uint(f);
  u += 0x7FFFu + ((u >> 16) & 1u);
  return (ushort)(u >> 16);
}
__device__ inline float bf2f(ushort h) {
  return __uint_as_float(((uint)h) << 16);
}

#define GLD_LDS16(g, s) __builtin_amdgcn_global_load_lds(                      \
    (const __attribute__((address_space(1))) void*)(g),                        \
    (__attribute__((address_space(3))) void*)(s), 16, 0, 0)

// ---------------------------------------------------------------------------
// f32 -> bf16 copy (n8 = elements/8)
// ---------------------------------------------------------------------------
__global__ __launch_bounds__(256)
void cvt_bf16(const float* __restrict__ x, ushort* __restrict__ y, int n8) {
  int i = blockIdx.x * 256 + threadIdx.x;
  if (i >= n8) return;
  const float4* xp = (const float4*)x;
  float4 a = xp[2 * i], b = xp[2 * i + 1];
  uint4 o;
  o.x = (uint)f2bf(a.x) | ((uint)f2bf(a.y) << 16);
  o.y = (uint)f2bf(a.z) | ((uint)f2bf(a.w) << 16);
  o.z = (uint)f2bf(b.x) | ((uint)f2bf(b.y) << 16);
  o.w = (uint)f2bf(b.z) | ((uint)f2bf(b.w) << 16);
  ((uint4*)y)[i] = o;
}

// ---------------------------------------------------------------------------
// f32 [R][C] -> bf16 [C][R] transpose (weights). Grid (C/32, R/32), 256 thr.
// ---------------------------------------------------------------------------
__global__ __launch_bounds__(256)
void cvt_t(const float* __restrict__ x, ushort* __restrict__ y, int R, int C) {
  __shared__ float tile[32][33];
  int r0 = blockIdx.y * 32, c0 = blockIdx.x * 32;
  int tr = threadIdx.x >> 5;       // 0..7
  int tc = threadIdx.x & 31;
  #pragma unroll
  for (int rr = tr; rr < 32; rr += 8)
    tile[rr][tc] = x[(size_t)(r0 + rr) * C + c0 + tc];
  __syncthreads();
  #pragma unroll
  for (int rr = tr; rr < 32; rr += 8)
    y[(size_t)(c0 + rr) * R + r0 + tc] = f2bf(tile[tc][rr]);
}

// ---------------------------------------------------------------------------
// bf16 MFMA GEMM: C[M,N] = A[M,K] @ BT[N,K]^T.  Grid MUST be (8, M/128).
// XOR-swizzled LDS (R8, conflict-free + coalesced) + XCD x-band block swizzle
// (each XCD owns one n-band -> B stays in its L2).
// ---------------------------------------------------------------------------
template<int ACC>
__global__ __launch_bounds__(256)
void gemm_bf(const ushort* __restrict__ A, const ushort* __restrict__ BT,
             float* __restrict__ C, int K, int lda, int ldbt, int ldc) {
  __shared__ ushort Asm[128 * 32];
  __shared__ ushort Bsm[128 * 32];
  const int t = threadIdx.x;
  const int w = t >> 6, l = t & 63;
  // XCD swizzle: linear id -> (x = id&7 band, y = id>>3); bijective for 8*64
  const int bid = blockIdx.y * 8 + blockIdx.x;
  const int m0 = (bid >> 3) * 128, n0 = (bid & 7) * 128;
  const int wr = w >> 1, wc = w & 1;
  const int srow = l >> 2;                    // staging row within subtile
  const int sgc  = (l & 3) ^ ((l >> 3) & 3);  // swizzled staging col-group
  const int ridx = (l & 15) * 32 + (((l >> 4) ^ ((l >> 1) & 3)) * 8);

  floatx4 acc[4][4];
  #pragma unroll
  for (int i = 0; i < 4; i++)
    #pragma unroll
    for (int j = 0; j < 4; j++)
      #pragma unroll
      for (int r = 0; r < 4; r++) acc[i][j][r] = 0.f;

  for (int k0 = 0; k0 < K; k0 += 32) {
    __syncthreads();
    #pragma unroll
    for (int j = 0; j < 2; j++) {
      int sub = w * 2 + j;             // subtile 0..7
      GLD_LDS16(A + (size_t)(m0 + sub * 16 + srow) * lda + k0 + sgc * 8,
                Asm + sub * 512);
      GLD_LDS16(BT + (size_t)(n0 + sub * 16 + srow) * ldbt + k0 + sgc * 8,
                Bsm + sub * 512);
    }
    __syncthreads();
    bhalf8 af[4], bf_[4];
    #pragma unroll
    for (int i = 0; i < 4; i++)
      af[i] = *(const bhalf8*)&Asm[(wr * 4 + i) * 512 + ridx];
    #pragma unroll
    for (int j = 0; j < 4; j++)
      bf_[j] = *(const bhalf8*)&Bsm[(wc * 4 + j) * 512 + ridx];
    #pragma unroll
    for (int i = 0; i < 4; i++)
      #pragma unroll
      for (int j = 0; j < 4; j++)
        acc[i][j] = __builtin_amdgcn_mfma_f32_16x16x32_bf16(af[i], bf_[j],
                                                            acc[i][j], 0, 0, 0);
  }
  const int crow = (l >> 4) * 4;
  const int ccol = l & 15;
  #pragma unroll
  for (int i = 0; i < 4; i++)
    #pragma unroll
    for (int j = 0; j < 4; j++) {
      float* cp = &C[(size_t)(m0 + wr * 64 + i * 16 + crow) * ldc +
                     n0 + wc * 64 + j * 16 + ccol];
      #pragma unroll
      for (int r = 0; r < 4; r++) {
        if (ACC) cp[(size_t)r * ldc] += acc[i][j][r];
        else     cp[(size_t)r * ldc]  = acc[i][j][r];
      }
    }
}

// ---------------------------------------------------------------------------
// Fused router GEMM: Ch[8192,2048](bf16) =
//   gelu(sum_p A_p[8192,1024] @ W1T[2048,6144]^T + b1)
// Grid (16,64). XCD swizzle: each XCD owns a 256-col n-band (B-band ~3MB in
// its L2); A panels paired within XCD. Virtual K = 6144 over 6 A operands.
// ---------------------------------------------------------------------------
struct APtrs { const ushort* p[6]; };

__global__ __launch_bounds__(256)
void gemm_router(APtrs ap, const ushort* __restrict__ BT,
                 const float* __restrict__ bias, ushort* __restrict__ Ch) {
  __shared__ ushort Asm[128 * 32];
  __shared__ ushort Bsm[128 * 32];
  const int t = threadIdx.x;
  const int w = t >> 6, l = t & 63;
  // bijective swizzle for 1024 blocks: xcd = id&7 -> x in {2c,2c+1}, y = all
  const int bid = blockIdx.y * 16 + blockIdx.x;
  const int xcd = bid & 7, idx = bid >> 3;
  const int m0 = (idx >> 1) * 128, n0 = (xcd * 2 + (idx & 1)) * 128;
  const int wr = w >> 1, wc = w & 1;
  const int srow = l >> 2;
  const int sgc  = (l & 3) ^ ((l >> 3) & 3);
  const int ridx = (l & 15) * 32 + (((l >> 4) ^ ((l >> 1) & 3)) * 8);

  floatx4 acc[4][4];
  #pragma unroll
  for (int i = 0; i < 4; i++)
    #pragma unroll
    for (int j = 0; j < 4; j++)
      #pragma unroll
      for (int r = 0; r < 4; r++) acc[i][j][r] = 0.f;

  for (int k0 = 0; k0 < 6144; k0 += 32) {
    const ushort* Abase = ap.p[k0 >> 10];
    const int kk = k0 & 1023;
    __syncthreads();
    #pragma unroll
    for (int j = 0; j < 2; j++) {
      int sub = w * 2 + j;
      GLD_LDS16(Abase + (size_t)(m0 + sub * 16 + srow) * 1024 + kk + sgc * 8,
                Asm + sub * 512);
      GLD_LDS16(BT + (size_t)(n0 + sub * 16 + srow) * 6144 + k0 + sgc * 8,
                Bsm + sub * 512);
    }
    __syncthreads();
    bhalf8 af[4], bf_[4];
    #pragma unroll
    for (int i = 0; i < 4; i++)
      af[i] = *(const bhalf8*)&Asm[(wr * 4 + i) * 512 + ridx];
    #pragma unroll
    for (int j = 0; j < 4; j++)
      bf_[j] = *(const bhalf8*)&Bsm[(wc * 4 + j) * 512 + ridx];
    #pragma unroll
    for (int i = 0; i < 4; i++)
      #pragma unroll
      for (int j = 0; j < 4; j++)
        acc[i][j] = __builtin_amdgcn_mfma_f32_16x16x32_bf16(af[i], bf_[j],
                                                            acc[i][j], 0, 0, 0);
  }
  const int crow = (l >> 4) * 4;
  const int ccol = l & 15;
  #pragma unroll
  for (int i = 0; i < 4; i++)
    #pragma unroll
    for (int j = 0; j < 4; j++) {
      const int col = n0 + wc * 64 + j * 16 + ccol;
      const float bb = bias[col];
      ushort* cp = &Ch[(size_t)(m0 + wr * 64 + i * 16 + crow) * 2048 + col];
      #pragma unroll
      for (int r = 0; r < 4; r++) {
        float x = acc[i][j][r] + bb;
        cp[(size_t)r * 2048] =
            f2bf(0.5f * x * (1.f + erff(x * 0.70710678118654752f)));
      }
    }
}

// ---------------------------------------------------------------------------
// Causal depthwise conv (K=4) + SiLU.  x,y: (B*L, 1024) f32.
// ---------------------------------------------------------------------------
__global__ __launch_bounds__(256)
void conv4_silu(const float* __restrict__ x, const float* __restrict__ w,
                float* __restrict__ y) {
  int idx = blockIdx.x * 256 + threadIdx.x;
  int c = idx & 1023;
  int bl = idx >> 10;
  int l = bl & (LSEQ - 1);
  float w0 = w[c * 4 + 0], w1 = w[c * 4 + 1], w2 = w[c * 4 + 2], w3 = w[c * 4 + 3];
  float acc = x[idx] * w3;
  if (l >= 1) acc += x[idx - 1024] * w2;
  if (l >= 2) acc += x[idx - 2048] * w1;
  if (l >= 3) acc += x[idx - 3072] * w0;
  y[idx] = acc / (1.f + expf(-acc));
}

// ---------------------------------------------------------------------------
// Pack FIR weights transposed: fwTp[row][c], rows 0..2=f3(j), 3..9=f7(j),
// 10..24=f15(j), 25..55=f31(j).
// ---------------------------------------------------------------------------
__global__ __launch_bounds__(256)
void pack_fir(const float* __restrict__ f3w, const float* __restrict__ f7w,
              const float* __restrict__ f15w, const float* __restrict__ f31w,
              float* __restrict__ fwTp) {
  int i = blockIdx.x * 256 + threadIdx.x;   // 56*1024
  if (i >= 57344) return;
  int row = i >> 10, c = i & 1023;
  float val;
  if (row < 3)       val = f3w[c * 3 + row];
  else if (row < 10) val = f7w[c * 7 + (row - 3)];
  else if (row < 25) val = f15w[c * 15 + (row - 10)];
  else               val = f31w[c * 31 + (row - 25)];
  fwTp[i] = val;
}

// ---------------------------------------------------------------------------
// All 4 depthwise causal FIRs in one pass. bf16 outputs.
// ---------------------------------------------------------------------------
__global__ __launch_bounds__(256)
void fir_all(const float* __restrict__ v, const float* __restrict__ fwTp,
             ushort* __restrict__ y3, ushort* __restrict__ y7,
             ushort* __restrict__ y15, ushort* __restrict__ y31) {
  int idx = blockIdx.x * 256 + threadIdx.x;   // over 8192*1024
  int c = idx & 1023;
  int l = (idx >> 10) & (LSEQ - 1);
  float a3 = 0.f, a7 = 0.f, a15 = 0.f, a31 = 0.f;
  #pragma unroll
  for (int back = 30; back >= 0; back--) {
    float x = (l >= back) ? v[idx - back * 1024] : 0.f;
    a31 += x * fwTp[(25 + 30 - back) * 1024 + c];
    if (back <= 14) a15 += x * fwTp[(10 + 14 - back) * 1024 + c];
    if (back <= 6)  a7  += x * fwTp[(3 + 6 - back) * 1024 + c];
    if (back <= 2)  a3  += x * fwTp[(2 - back) * 1024 + c];
  }
  y3[idx]  = f2bf(a3);
  y7[idx]  = f2bf(a7);
  y15[idx] = f2bf(a15);
  y31[idx] = f2bf(a31);
}

// ---------------------------------------------------------------------------
// beta = sigmoid(hs@Wb), p_value = sigmoid(hs@idW + idb); one wave per (tok,h)
// ---------------------------------------------------------------------------
__global__ __launch_bounds__(256)
void beta_pv(const float* __restrict__ hs, const float* __restrict__ Wb,
             const float* __restrict__ idW, const float* __restrict__ idb,
             float* __restrict__ beta, float* __restrict__ pv) {
  int tok = blockIdx.x;
  int h = threadIdx.x >> 6;
  int lane = threadIdx.x & 63;
  const float* hrow = hs + (size_t)tok * 1024;
  float s1 = 0.f, s2 = 0.f;
  #pragma unroll
  for (int j = 0; j < 16; j++) {
    int d = lane + j * 64;
    float hv = hrow[d];
    s1 += hv * Wb[d * 4 + h];
    s2 += hv * idW[d * 4 + h];
  }
  #pragma unroll
  for (int off = 32; off; off >>= 1) {
    s1 += __shfl_down(s1, off);
    s2 += __shfl_down(s2, off);
  }
  if (lane == 0) {
    beta[tok * 4 + h] = 1.f / (1.f + expf(-s1));
    pv[tok * 4 + h] = 1.f / (1.f + expf(-(s2 + idb[h])));
  }
}

// ---------------------------------------------------------------------------
// In-place l2norm of q and k per (tok, head) over 256 dims. Wave per (tok,h).
// ---------------------------------------------------------------------------
__global__ __launch_bounds__(256)
void l2norm_qk(float* __restrict__ q, float* __restrict__ k) {
  int tok = blockIdx.x;
  int h = threadIdx.x >> 6;
  int lane = threadIdx.x & 63;
  size_t base = (size_t)tok * 1024 + h * 256 + lane * 4;
  {
    float4* p = (float4*)(q + base);
    float4 v = *p;
    float ss = v.x * v.x + v.y * v.y + v.z * v.z + v.w * v.w;
    #pragma unroll
    for (int off = 32; off; off >>= 1) ss += __shfl_xor(ss, off);
    float sc = rsqrtf(ss + 1e-6f);
    v.x *= sc; v.y *= sc; v.z *= sc; v.w *= sc;
    *p = v;
  }
  {
    float4* p = (float4*)(k + base);
    float4 v = *p;
    float ss = v.x * v.x + v.y * v.y + v.z * v.z + v.w * v.w;
    #pragma unroll
    for (int off = 32; off; off >>= 1) ss += __shfl_xor(ss, off);
    float sc = rsqrtf(ss + 1e-6f);
    v.x *= sc; v.y *= sc; v.z *= sc; v.w *= sc;
    *p = v;
  }
}

// ---------------------------------------------------------------------------
// Per-(b,h,chunk): att = tril(q k^T) [bf16 frag-order], forward substitution
// u = T^{-1}(v*beta) [f32], w = T^{-1}(k*beta) [bf16 frag-order],
// q and k^T [bf16 frag-order] for the MFMA scan.
// ---------------------------------------------------------------------------
__global__ __launch_bounds__(256)
void chunk_prep(const float* __restrict__ q, const float* __restrict__ k,
                const float* __restrict__ v, const float* __restrict__ beta,
                ushort* __restrict__ attf, float* __restrict__ ub,
                ushort* __restrict__ wfb, ushort* __restrict__ qfb,
                ushort* __restrict__ ktb) {
  __shared__ float kbuf[32 * 260];
  __shared__ float qbuf[32 * 260];
  __shared__ float Am[32 * 32];
  __shared__ float bet[32];
  const int t = threadIdx.x;
  const int blk = blockIdx.x;          // ((b*4+h)*64 + n)
  const int n = blk & 63, bh = blk >> 6;
  const int h = bh & 3, b = bh >> 2;
  const size_t rowbase = (size_t)b * LSEQ + n * 32;
  const int cbase = h * 256;
  const int srow = t >> 6, scol = (t & 63) * 4;
  const size_t fb = (size_t)blk * 8192;   // frag-buffer base (ushort)

  #pragma unroll
  for (int rep = 0; rep < 8; rep++) {
    int r = rep * 4 + srow;
    *(float4*)&kbuf[r * 260 + scol] =
        *(const float4*)&k[(rowbase + r) * 1024 + cbase + scol];
    *(float4*)&qbuf[r * 260 + scol] =
        *(const float4*)&q[(rowbase + r) * 1024 + cbase + scol];
  }
  if (t < 32) bet[t] = beta[(rowbase + t) * 4 + h];
  __syncthreads();

  // att (bf16 frag order) + A
  #pragma unroll
  for (int e = 0; e < 4; e++) {
    int idx = t + e * 256;
    int i = idx >> 5, jc = idx & 31;
    float da = 0.f, dq = 0.f;
    for (int d0 = 0; d0 < 256; d0 += 4) {
      float4 kj = *(float4*)&kbuf[jc * 260 + d0];
      float4 ki = *(float4*)&kbuf[i * 260 + d0];
      float4 qi = *(float4*)&qbuf[i * 260 + d0];
      da += ki.x * kj.x + ki.y * kj.y + ki.z * kj.z + ki.w * kj.w;
      dq += qi.x * kj.x + qi.y * kj.y + qi.z * kj.z + qi.w * kj.w;
    }
    Am[i * 32 + jc] = (jc < i) ? bet[i] * da : 0.f;
    float av = (jc <= i) ? dq : 0.f;
    attf[(size_t)blk * 1024 + (i >> 4) * 512 +
         ((i & 15) + ((jc >> 3) & 3) * 16) * 8 + (jc & 7)] = f2bf(av);
  }
  __syncthreads();

  // k^T frag writes (A-operand, M=dk 256, K=c 32), pre-substitution.
  #pragma unroll
  for (int cg = 0; cg < 4; cg++) {
    bhalf8 pk;
    #pragma unroll
    for (int j = 0; j < 8; j++)
      pk[j] = (short)f2bf(kbuf[(cg * 8 + j) * 260 + t]);
    *(bhalf8*)&ktb[fb + (t >> 4) * 512 + ((t & 15) + cg * 16) * 8] = pk;
  }

  // k -> w in place (thread owns column t; column-private)
  #pragma unroll 1
  for (int i = 0; i < 32; i++) {
    float val = bet[i] * kbuf[i * 260 + t];
    for (int j = 0; j < i; j++) val -= Am[i * 32 + j] * kbuf[j * 260 + t];
    kbuf[i * 260 + t] = val;
  }
  __syncthreads();   // w stable for cross-column repack

  // w and q frag repack: pack p -> (c = p&31, dk8 = p>>5)
  #pragma unroll
  for (int rep = 0; rep < 4; rep++) {
    int p = rep * 256 + t;
    int c = p & 31, dk8 = p >> 5;
    size_t pos = fb + ((size_t)(dk8 >> 2) * 2 + (c >> 4)) * 512 +
                 ((c & 15) + (dk8 & 3) * 16) * 8;
    bhalf8 pw, pq;
    #pragma unroll
    for (int j = 0; j < 8; j++) {
      pw[j] = (short)f2bf(kbuf[c * 260 + dk8 * 8 + j]);
      pq[j] = (short)f2bf(qbuf[c * 260 + dk8 * 8 + j]);
    }
    *(bhalf8*)&wfb[pos] = pw;
    *(bhalf8*)&qfb[pos] = pq;
  }
  __syncthreads();

  // v into qbuf, then v -> u (f32)
  #pragma unroll
  for (int rep = 0; rep < 8; rep++) {
    int r = rep * 4 + srow;
    *(float4*)&qbuf[r * 260 + scol] =
        *(const float4*)&v[(rowbase + r) * 1024 + cbase + scol];
  }
  __syncthreads();
  #pragma unroll 1
  for (int i = 0; i < 32; i++) {
    float val = bet[i] * qbuf[i * 260 + t];
    for (int j = 0; j < i; j++) val -= Am[i * 32 + j] * qbuf[j * 260 + t];
    qbuf[i * 260 + t] = val;
  }
  for (int j = 0; j < 32; j++)
    ub[(rowbase + j) * 1024 + cbase + t] = qbuf[j * 260 + t];
}

// ---------------------------------------------------------------------------
// MFMA delta scan. Block per (b,h,dv-slice of 16): 256 blocks, 4 waves.
// S (256x16) lives as f32 MFMA accumulators (4 frags/wave, K-split by wave).
// ---------------------------------------------------------------------------
__global__ __launch_bounds__(256)
void delta_scan(const ushort* __restrict__ wfb, const ushort* __restrict__ qfb,
                const ushort* __restrict__ ktb, const ushort* __restrict__ attf,
                const float* __restrict__ ub, ushort* __restrict__ outb) {
  __shared__ ushort wS[8192];
  __shared__ ushort qS[8192];
  __shared__ ushort kTS[8192];
  __shared__ ushort attS[1024];
  __shared__ ushort SbT[16 * 264];
  __shared__ ushort uaT[16 * 40];
  __shared__ float pbufW[4 * 544];
  __shared__ float pbufQ[4 * 544];
  __shared__ float oacc[544];
  const int t = threadIdx.x;
  const int w = t >> 6, l = t & 63;
  const int col16 = l & 15, g = l >> 4;
  const int blk = blockIdx.x;
  const int dsl = blk & 15, bh = blk >> 4;
  const int h = bh & 3, b = bh >> 2;
  const int dbase = h * 256 + dsl * 16;

  floatx4 S_acc[4];
  #pragma unroll
  for (int m = 0; m < 4; m++)
    #pragma unroll
    for (int r = 0; r < 4; r++) S_acc[m][r] = 0.f;

  for (int n = 0; n < NCHUNK; n++) {
    const size_t cb = ((size_t)(bh * 64 + n)) * 8192;
    const size_t ab = ((size_t)(bh * 64 + n)) * 1024;
    const size_t rowbase = (size_t)b * LSEQ + n * 32;

    // SbT <- bf16(S_acc): lane holds rows w*64+m*16+g*4+{0..3}, col col16
    #pragma unroll
    for (int m = 0; m < 4; m++) {
      uint lo = (uint)f2bf(S_acc[m][0]) | ((uint)f2bf(S_acc[m][1]) << 16);
      uint hi = (uint)f2bf(S_acc[m][2]) | ((uint)f2bf(S_acc[m][3]) << 16);
      uint2 pk; pk.x = lo; pk.y = hi;
      *(uint2*)&SbT[col16 * 264 + w * 64 + m * 16 + g * 4] = pk;
    }
    // stage w/q/kT (16 KB each) + att (2 KB) via global_load_lds
    #pragma unroll
    for (int i = 0; i < 4; i++) {
      GLD_LDS16(wfb + cb + (w * 4 + i) * 512 + l * 8, &wS[(w * 4 + i) * 512]);
      GLD_LDS16(qfb + cb + (w * 4 + i) * 512 + l * 8, &qS[(w * 4 + i) * 512]);
      GLD_LDS16(ktb + cb + (w * 4 + i) * 512 + l * 8, &kTS[(w * 4 + i) * 512]);
    }
    if (w == 2) {
      GLD_LDS16(attf + ab + l * 8, &attS[0]);
      GLD_LDS16(attf + ab + 512 + l * 8, &attS[512]);
    }
    float u0 = ub[(rowbase + (t >> 4)) * 1024 + dbase + (t & 15)];
    float u1 = ub[(rowbase + 16 + (t >> 4)) * 1024 + dbase + (t & 15)];
    __syncthreads();

    // phase 1: partial w@S and q@S over this wave's K-slice (64 rows of S)
    floatx4 pw0, pw1, pq0, pq1;
    #pragma unroll
    for (int r = 0; r < 4; r++) { pw0[r] = 0.f; pw1[r] = 0.f; pq0[r] = 0.f; pq1[r] = 0.f; }
    #pragma unroll
    for (int s = 0; s < 2; s++) {
      const int koff = w * 2 + s;               // kstep 0..7
      bhalf8 sb = *(const bhalf8*)&SbT[col16 * 264 + koff * 32 + g * 8];
      bhalf8 wa0 = *(const bhalf8*)&wS[((koff * 2 + 0) * 64 + l) * 8];
      bhalf8 wa1 = *(const bhalf8*)&wS[((koff * 2 + 1) * 64 + l) * 8];
      bhalf8 qa0 = *(const bhalf8*)&qS[((koff * 2 + 0) * 64 + l) * 8];
      bhalf8 qa1 = *(const bhalf8*)&qS[((koff * 2 + 1) * 64 + l) * 8];
      pw0 = __builtin_amdgcn_mfma_f32_16x16x32_bf16(wa0, sb, pw0, 0, 0, 0);
      pw1 = __builtin_amdgcn_mfma_f32_16x16x32_bf16(wa1, sb, pw1, 0, 0, 0);
      pq0 = __builtin_amdgcn_mfma_f32_16x16x32_bf16(qa0, sb, pq0, 0, 0, 0);
      pq1 = __builtin_amdgcn_mfma_f32_16x16x32_bf16(qa1, sb, pq1, 0, 0, 0);
    }
    #pragma unroll
    for (int r = 0; r < 4; r++) {
      pbufW[w * 544 + (g * 4 + r) * 17 + col16] = pw0[r];
      pbufW[w * 544 + (16 + g * 4 + r) * 17 + col16] = pw1[r];
      pbufQ[w * 544 + (g * 4 + r) * 17 + col16] = pq0[r];
      pbufQ[w * 544 + (16 + g * 4 + r) * 17 + col16] = pq1[r];
    }
    __syncthreads();

    // phase 2: reduce partials -> ua (bf16, B-layout) and oacc = q@S
    {
      const int row = t >> 4, c2 = t & 15;
      const int i0 = row * 17 + c2, i1 = (row + 16) * 17 + c2;
      float wsA = pbufW[i0] + pbufW[544 + i0] + pbufW[1088 + i0] + pbufW[1632 + i0];
      float wsB = pbufW[i1] + pbufW[544 + i1] + pbufW[1088 + i1] + pbufW[1632 + i1];
      float qsA = pbufQ[i0] + pbufQ[544 + i0] + pbufQ[1088 + i0] + pbufQ[1632 + i0];
      float qsB = pbufQ[i1] + pbufQ[544 + i1] + pbufQ[1088 + i1] + pbufQ[1632 + i1];
      oacc[i0] = qsA;
      oacc[i1] = qsB;
      uaT[c2 * 40 + row] = f2bf(u0 - wsA);
      uaT[c2 * 40 + row + 16] = f2bf(u1 - wsB);
    }
    __syncthreads();

    // phase 3: S += k^T @ ua (MFMA accumulate); o = oacc + att@ua -> global
    bhalf8 uB = *(const bhalf8*)&uaT[col16 * 40 + g * 8];
    #pragma unroll
    for (int m = 0; m < 4; m++) {
      bhalf8 ka = *(const bhalf8*)&kTS[((w * 4 + m) * 64 + l) * 8];
      S_acc[m] = __builtin_amdgcn_mfma_f32_16x16x32_bf16(ka, uB, S_acc[m], 0, 0, 0);
    }
    if (w < 2) {
      floatx4 z;
      #pragma unroll
      for (int r = 0; r < 4; r++) z[r] = 0.f;
      bhalf8 aa = *(const bhalf8*)&attS[(w * 64 + l) * 8];
      floatx4 oat = __builtin_amdgcn_mfma_f32_16x16x32_bf16(aa, uB, z, 0, 0, 0);
      #pragma unroll
      for (int r = 0; r < 4; r++) {
        int row = w * 16 + g * 4 + r;
        float ov = oacc[row * 17 + col16] + oat[r];
        outb[(rowbase + row) * 1024 + dbase + col16] = f2bf(ov);
      }
    }
    __syncthreads();
  }
}

// ---------------------------------------------------------------------------
// logits = hmid(bf16)[tok] @ W2 + b2 (20 cols), K=2048 single pass.
// ---------------------------------------------------------------------------
__global__ __launch_bounds__(256)
void logits_one(const ushort* __restrict__ hmid, const float* __restrict__ W2,
                const float* __restrict__ b2, float* __restrict__ logits) {
  __shared__ float hrow[2048];
  __shared__ float part[8][20];
  int tok = blockIdx.x, t = threadIdx.x;
  {
    uint4 hv = ((const uint4*)(hmid + (size_t)tok * 2048))[t];  // 8 bf16
    const ushort* hp = (const ushort*)&hv;
    #pragma unroll
    for (int j = 0; j < 8; j++) hrow[t * 8 + j] = bf2f(hp[j]);
  }
  __syncthreads();
  if (t < 160) {
    int col = t % 20, seg = t / 20;
    float acc = 0.f;
    for (int kk = 0; kk < 256; kk++) {
      int k2 = seg * 256 + kk;
      acc += hrow[k2] * W2[(size_t)k2 * 20 + col];
    }
    part[seg][col] = acc;
  }
  __syncthreads();
  if (t < 20) {
    float s = b2[t];
    #pragma unroll
    for (int g = 0; g < 8; g++) s += part[g][t];
    logits[(size_t)tok * 20 + t] = s;
  }
}

// ---------------------------------------------------------------------------
// probs = softmax(logits / tau) per (tok, head); one thread per (tok,h)
// ---------------------------------------------------------------------------
__global__ __launch_bounds__(256)
void softmax_probs(const float* __restrict__ logits, const float* __restrict__ ltau,
                   float* __restrict__ probs) {
  int idx = blockIdx.x * 256 + threadIdx.x;   // 32768
  int tok = idx >> 2, h = idx & 3;
  float tau = expf(ltau[h]);
  tau = tau < 0.5f ? 0.5f : tau;
  float x[5]; float m = -1e30f;
  #pragma unroll
  for (int i = 0; i < 5; i++) {
    x[i] = logits[(size_t)tok * 20 + h * 5 + i] / tau;
    m = fmaxf(m, x[i]);
  }
  float s = 0.f;
  #pragma unroll
  for (int i = 0; i < 5; i++) { x[i] = expf(x[i] - m); s += x[i]; }
  float inv = 1.f / s;
  #pragma unroll
  for (int i = 0; i < 5; i++) probs[(size_t)tok * 20 + h * 5 + i] = x[i] * inv;
}

// ---------------------------------------------------------------------------
// Mix 5 bf16 paths + f32 v with router probs + value gate, per-head RMSNorm,
// write bf16 omix. One wave per (tok, head).
// ---------------------------------------------------------------------------
__global__ __launch_bounds__(256)
void mix_rms(const ushort* __restrict__ f3, const ushort* __restrict__ f7,
             const ushort* __restrict__ f15, const ushort* __restrict__ f31,
             const ushort* __restrict__ dlt, const float* __restrict__ v,
             const float* __restrict__ probs, const float* __restrict__ pv,
             const float* __restrict__ onw, ushort* __restrict__ omix) {
  int tok = blockIdx.x;
  int h = threadIdx.x >> 6;
  int lane = threadIdx.x & 63;
  size_t base = (size_t)tok * 1024 + h * 256 + lane * 4;
  const float* pp = probs + (size_t)tok * 20 + h * 5;
  float p0 = pp[0], p1 = pp[1], p2 = pp[2], p3 = pp[3], p4 = pp[4];
  float pvv = pv[tok * 4 + h];
  float floor_tok = 0.01f + 0.09f * (1.f - pvv);
  float pa = (1.f - floor_tok) * pvv;
  float cm = 1.f - pa;
  ushort4 a4 = *(const ushort4*)&f3[base];
  ushort4 b4 = *(const ushort4*)&f7[base];
  ushort4 c4 = *(const ushort4*)&f15[base];
  ushort4 d4 = *(const ushort4*)&f31[base];
  ushort4 e4 = *(const ushort4*)&dlt[base];
  float4 vv = *(const float4*)&v[base];
  float av[4] = {bf2f(a4.x), bf2f(a4.y), bf2f(a4.z), bf2f(a4.w)};
  float bv[4] = {bf2f(b4.x), bf2f(b4.y), bf2f(b4.z), bf2f(b4.w)};
  float cv[4] = {bf2f(c4.x), bf2f(c4.y), bf2f(c4.z), bf2f(c4.w)};
  float dv[4] = {bf2f(d4.x), bf2f(d4.y), bf2f(d4.z), bf2f(d4.w)};
  float ev[4] = {bf2f(e4.x), bf2f(e4.y), bf2f(e4.z), bf2f(e4.w)};
  float vvv[4] = {vv.x, vv.y, vv.z, vv.w};
  float o[4];
  #pragma unroll
  for (int j = 0; j < 4; j++)
    o[j] = cm * (p0 * av[j] + p1 * bv[j] + p2 * cv[j] + p3 * dv[j] + p4 * ev[j]) +
           pa * vvv[j];
  float ss = o[0]*o[0] + o[1]*o[1] + o[2]*o[2] + o[3]*o[3];
  #pragma unroll
  for (int off = 32; off; off >>= 1) ss += __shfl_xor(ss, off);
  float sc = rsqrtf(ss * (1.f / 256.f) + 1e-5f);
  float4 wn = *(const float4*)&onw[lane * 4];
  ushort4 res;
  res.x = f2bf(o[0] * sc * wn.x); res.y = f2bf(o[1] * sc * wn.y);
  res.z = f2bf(o[2] * sc * wn.z); res.w = f2bf(o[3] * sc * wn.w);
  *(ushort4*)&omix[base] = res;
}

// ---------------------------------------------------------------------------
extern "C" void kernel_launch(void* const* d_in, const int* in_sizes, int n_in,
                              void* d_out, int out_size, void* d_ws, size_t ws_size,
                              hipStream_t stream) {
  const float* hs  = (const float*)d_in[0];
  const float* Wq  = (const float*)d_in[1];
  const float* Wk  = (const float*)d_in[2];
  const float* Wv  = (const float*)d_in[3];
  const float* qcw = (const float*)d_in[4];
  const float* kcw = (const float*)d_in[5];
  const float* vcw = (const float*)d_in[6];
  const float* Wb  = (const float*)d_in[7];
  const float* f3w = (const float*)d_in[8];
  const float* f7w = (const float*)d_in[9];
  const float* f15w= (const float*)d_in[10];
  const float* f31w= (const float*)d_in[11];
  const float* rW1 = (const float*)d_in[12];
  const float* rb1 = (const float*)d_in[13];
  const float* rW2 = (const float*)d_in[14];
  const float* rb2 = (const float*)d_in[15];
  const float* igW = (const float*)d_in[16];
  const float* igb = (const float*)d_in[17];
  const float* ltau= (const float*)d_in[18];
  const float* onw = (const float*)d_in[19];
  const float* Wo  = (const float*)d_in[20];
  float* out = (float*)d_out;
  float* ws  = (float*)d_ws;

  // f32 regions (floats from ws base); total ~241 MB (same as passing R2-R8)
  float* pre    = ws;              // phaseA scratch -> ktb+attf -> hmid(bf16)
  float* qb     = ws +  8388608;   // q f32 -> W1T
  float* kb     = ws + 16777216;   // k f32 -> hs_bf2 + WoT
  float* vb     = ws + 25165824;   // v f32 (live to mix)
  float* ub     = ws + 33554432;   // phaseA bf16 staging -> u f32 -> f3b/f7b
  float* wbuf   = ws + 41943040;   // wfb+qfb -> f15b/f31b
  float* dlt    = ws + 50331648;   // dltb (bf16) + omixb (bf16)
  float* fwTp   = ws + 58720256;   // 57,344 floats (free ex-attb gap)
  float* beta   = ws + 59768832;
  float* pv     = ws + 59801600;
  float* logits = ws + 59834368;
  float* probs  = ws + 59998208;

  // bf16 aliases
  ushort* hs_bf1 = (ushort*)ub;
  ushort* WqT    = (ushort*)(ub + 4194304);
  ushort* WkT    = WqT + 1048576;
  ushort* WvT    = WkT + 1048576;
  ushort* ktb    = (ushort*)pre;                 // 1024*8192 us
  ushort* attfb  = (ushort*)(pre + 4194304);     // 1024*1024 us
  ushort* wfb    = (ushort*)wbuf;                // 1024*8192 us
  ushort* qfb    = (ushort*)(wbuf + 4194304);
  ushort* f3b    = (ushort*)ub;
  ushort* f7b    = (ushort*)(ub + 4194304);
  ushort* f15b   = (ushort*)wbuf;
  ushort* f31b   = (ushort*)(wbuf + 4194304);
  ushort* dltb   = (ushort*)dlt;
  ushort* omixb  = (ushort*)(dlt + 4194304);
  ushort* hs_bf2 = (ushort*)kb;
  ushort* WoT    = (ushort*)(kb + 4194304);
  ushort* W1T    = (ushort*)qb;
  ushort* hmidb  = (ushort*)pre;   // 8192*2048 bf16 = full pre region

  dim3 blk(256);
  dim3 gg(8, 64);      // 1024-N GEMM tiles
  dim3 gg2(16, 64);    // fused 2048-N router

  // ---- phase A: q/k/v projections (bf16 MFMA) + conv + silu ----
  cvt_bf16<<<4096, blk, 0, stream>>>(hs, hs_bf1, 1048576);
  cvt_t<<<dim3(32, 32), blk, 0, stream>>>(Wq, WqT, 1024, 1024);
  cvt_t<<<dim3(32, 32), blk, 0, stream>>>(Wk, WkT, 1024, 1024);
  cvt_t<<<dim3(32, 32), blk, 0, stream>>>(Wv, WvT, 1024, 1024);
  gemm_bf<0><<<gg, blk, 0, stream>>>(hs_bf1, WqT, pre, 1024, 1024, 1024, 1024);
  conv4_silu<<<32768, blk, 0, stream>>>(pre, qcw, qb);
  gemm_bf<0><<<gg, blk, 0, stream>>>(hs_bf1, WkT, pre, 1024, 1024, 1024, 1024);
  conv4_silu<<<32768, blk, 0, stream>>>(pre, kcw, kb);
  gemm_bf<0><<<gg, blk, 0, stream>>>(hs_bf1, WvT, pre, 1024, 1024, 1024, 1024);
  conv4_silu<<<32768, blk, 0, stream>>>(pre, vcw, vb);

  beta_pv<<<8192, blk, 0, stream>>>(hs, Wb, igW, igb, beta, pv);
  l2norm_qk<<<8192, blk, 0, stream>>>(qb, kb);

  // ---- delta rule ----
  chunk_prep<<<1024, blk, 0, stream>>>(qb, kb, vb, beta, attfb, ub, wfb, qfb, ktb);
  delta_scan<<<256, blk, 0, stream>>>(wfb, qfb, ktb, attfb, ub, dltb);

  // ---- FIR paths: fused, transposed weights (bf16 out) ----
  pack_fir<<<224, blk, 0, stream>>>(f3w, f7w, f15w, f31w, fwTp);
  fir_all<<<32768, blk, 0, stream>>>(vb, fwTp, f3b, f7b, f15b, f31b);

  // ---- conversions for router ----
  cvt_bf16<<<4096, blk, 0, stream>>>(hs, hs_bf2, 1048576);
  cvt_t<<<dim3(64, 192), blk, 0, stream>>>(rW1, W1T, 6144, 2048);
  cvt_t<<<dim3(32, 32), blk, 0, stream>>>(Wo, WoT, 1024, 1024);

  // ---- fused router GEMM (N=2048, bias+gelu, bf16 out) + logits ----
  APtrs ap;
  ap.p[0] = hs_bf2; ap.p[1] = f3b; ap.p[2] = f7b;
  ap.p[3] = f15b;   ap.p[4] = f31b; ap.p[5] = dltb;
  gemm_router<<<gg2, blk, 0, stream>>>(ap, W1T, rb1, hmidb);
  logits_one<<<8192, blk, 0, stream>>>(hmidb, rW2, rb2, logits);
  softmax_probs<<<128, blk, 0, stream>>>(logits, ltau, probs);

  // ---- mix + RMSNorm (bf16 out) + output projection ----
  mix_rms<<<8192, blk, 0, stream>>>(f3b, f7b, f15b, f31b, dltb, vb, probs, pv,
                                    onw, omixb);
  gemm_bf<0><<<gg, blk, 0, stream>>>(omixb, WoT, out, 1024, 1024, 1024, 1024);
}